// Round 8
// baseline (8977.515 us; speedup 1.0000x reference)
//
#include <hip/hip_runtime.h>
#include <hip/hip_cooperative_groups.h>

#define NSTEPS 200

typedef __attribute__((ext_vector_type(8))) short bf16x8;
typedef __attribute__((ext_vector_type(4))) float f32x4;

__device__ __forceinline__ float sigm(float x){ return 1.0f/(1.0f + __expf(-x)); }

__device__ __forceinline__ unsigned short f2bf(float f){
  unsigned int u = __float_as_uint(f);
  u = u + 0x7FFFu + ((u>>16)&1u);
  return (unsigned short)(u>>16);
}
__device__ __forceinline__ float bf2f(unsigned short s){
  return __uint_as_float(((unsigned int)s)<<16);
}

__device__ __forceinline__ void gld_lds16(const void* g, void* l){
  __builtin_amdgcn_global_load_lds(
    (const __attribute__((address_space(1))) unsigned int*)g,
    (__attribute__((address_space(3))) unsigned int*)l, 16, 0, 0);
}

// ---------------- zero row pads of a padded bf16 activation buffer ----------------
__global__ __launch_bounds__(256) void zpad_k(unsigned short* __restrict__ p, int nrows, int L){
  int idx = blockIdx.x*256 + threadIdx.x;
  if(idx >= nrows*8) return;
  int row = idx>>3; int j = idx&7;
  int off = (j<4) ? j*4 : (16 + L + (j-4)*4);
  ushort4 z; z.x=0; z.y=0; z.z=0; z.w=0;
  *(ushort4*)&p[(size_t)row*(L+32) + off] = z;
}

// ---------------- pack conv weights: fp32 [CO][CI][31] -> bf16 [CO][CI*32] (slot0=0) ----------------
__global__ __launch_bounds__(256) void packw_k(const float* __restrict__ w, unsigned short* __restrict__ wpk, int total){
  int idx = blockIdx.x*256 + threadIdx.x;
  if(idx >= total) return;
  int k = idx & 31; int r = idx >> 5;
  wpk[idx] = (k >= 1) ? f2bf(w[(size_t)r*31 + (k-1)]) : (unsigned short)0;
}

// ---------------- conv0: Cin=1, Cout=64, L 8192->2048, fp32 VALU, bf16 padded out ----------------
__global__ __launch_bounds__(256) void conv0_k(const float* __restrict__ x,
    const float* __restrict__ w, const float* __restrict__ bias, unsigned short* __restrict__ act0){
  __shared__ float xl[1056];
  __shared__ float wl[64*31];
  __shared__ float bl[64];
  int b = blockIdx.x >> 3; int lt = blockIdx.x & 7;
  int l0 = lt*256; int tid = threadIdx.x;
  for(int i=tid;i<1056;i+=256){
    int g = 4*l0 - 15 + i;
    xl[i] = (g>=0 && g<8192) ? x[(size_t)b*8192 + g] : 0.f;
  }
  for(int i=tid;i<1984;i+=256) wl[i] = w[i];
  if(tid<64) bl[tid]=bias[tid];
  __syncthreads();
  float xr[31];
  #pragma unroll
  for(int j=0;j<31;j++) xr[j] = xl[4*tid + j];
  size_t obase = ((size_t)b*64)*2080 + 16 + l0 + tid;
  for(int co=0;co<64;co++){
    float acc = bl[co];
    #pragma unroll
    for(int j=0;j<31;j++) acc = fmaf(wl[co*31+j], xr[j], acc);
    act0[obase + (size_t)co*2080] = f2bf(fmaxf(acc,0.f));
  }
}

// ---------------- generic MFMA conv (as GEMM M=(b,l), N=co, K=ci*32+tap) ----------------
template<int CIN, int LIN, int LOUT, int LT, int NBT, int COUT, int KSPLIT>
__global__ __launch_bounds__(256,3) void conv_mfma_k(
    const unsigned short* __restrict__ actin,
    const unsigned short* __restrict__ wpk,
    const float* __restrict__ bias,
    unsigned short* __restrict__ actout,
    float* __restrict__ partial)
{
  constexpr int LINP  = LIN + 32;
  constexpr int LOUTP = LOUT + 32;
  constexpr int SPANB = 8*LT + 64;
  constexpr int SC    = SPANB/16;
  constexpr int CA    = 2*NBT*SC;
  static_assert(CA <= 256, "CA");
  constexpr int ASZ   = CA*16;
  constexpr int BSZ   = 16384;
  constexpr int MT    = 128*LOUT;
  constexpr int MTILES= MT/128;
  constexpr int NT    = COUT/128;
  constexpr int NSTEP = CIN/2/KSPLIT;
  constexpr int GRID  = MTILES*NT*KSPLIT;
  static_assert(GRID % 8 == 0, "grid%8");
  __shared__ __align__(16) char smem[2*(BSZ+ASZ)];
  char* Bb = smem;
  char* Ab = smem + 2*BSZ;

  // XCD-aware swizzle: hw round-robins bid%8 across XCDs; map so consecutive
  // LOGICAL bids (which share the (nt,z) weight slice) land on ONE XCD.
  int bid = (blockIdx.x & 7)*(GRID/8) + (blockIdx.x >> 3);
  int mt = bid % MTILES; bid /= MTILES;
  int nt = bid % NT;     int z = bid / NT;
  int b0 = (mt*128)/LOUT;
  int l0 = (mt*128)%LOUT;
  int cobase = nt*128;
  int s0 = z*NSTEP, s1 = s0 + NSTEP;

  int tid = threadIdx.x; int lane = tid&63; int wid = tid>>6;
  int wm = wid>>1, wn = wid&1;
  int l15 = lane&15, kg = lane>>4;

  int aq_c=0, aq_b=0, aq_j=0; bool a_act = tid < CA;
  { int q = tid; aq_c = q/(NBT*SC); int r = q%(NBT*SC); aq_b = r/SC; aq_j = r%SC; }

  auto STAGE = [&](int st){
    int buf = st&1;
    #pragma unroll
    for(int i=0;i<4;i++){
      int qb = tid + i*256;
      int col = qb>>3; int j = qb&7;
      const char* src = (const char*)wpk + (size_t)(cobase+col)*(CIN*64) + (size_t)st*128
                        + ((j*16) ^ ((col&7)<<4));
      gld_lds16(src, Bb + buf*BSZ + qb*16);
    }
    if(a_act){
      int ci = 2*st + aq_c;
      const char* src = (const char*)actin
          + 2*((size_t)((b0+aq_b)*CIN + ci)*LINP + 4*l0) + aq_j*16;
      gld_lds16(src, Ab + buf*ASZ + tid*16);
    }
  };

  int abyte[2][4], bbyte[2][4];
  #pragma unroll
  for(int c=0;c<2;c++){
    #pragma unroll
    for(int mf=0;mf<4;mf++){
      int r = wm*64 + mf*16 + l15;
      int bp = (NBT>1) ? (r/LT) : 0;
      int ll = (NBT>1) ? (r%LT) : r;
      abyte[c][mf] = (c*NBT + bp)*SPANB + 8*ll + 16*kg;
    }
    #pragma unroll
    for(int nf=0;nf<4;nf++){
      int col = wn*64 + nf*16 + l15;
      bbyte[c][nf] = col*128 + ((c*64 + 16*kg) ^ ((col&7)<<4));
    }
  }

  const f32x4 vz = {0.f,0.f,0.f,0.f};
  f32x4 acc[4][4];
  #pragma unroll
  for(int i=0;i<4;i++)
    #pragma unroll
    for(int j=0;j<4;j++) acc[i][j] = vz;

  STAGE(s0);
  __syncthreads();
  for(int s=s0;s<s1;s++){
    if(s+1<s1) STAGE(s+1);
    const char* Ac = Ab + (s&1)*ASZ;
    const char* Bc = Bb + (s&1)*BSZ;
    #pragma unroll
    for(int c=0;c<2;c++){
      bf16x8 af[4], bfv[4];
      #pragma unroll
      for(int mf=0;mf<4;mf++){
        const char* ap = Ac + abyte[c][mf];
        union { unsigned long long u[2]; bf16x8 v; } t;
        t.u[0] = *(const unsigned long long*)ap;
        t.u[1] = *(const unsigned long long*)(ap+8);
        af[mf] = t.v;
      }
      #pragma unroll
      for(int nf=0;nf<4;nf++) bfv[nf] = *(const bf16x8*)(Bc + bbyte[c][nf]);
      #pragma unroll
      for(int mf=0;mf<4;mf++)
        #pragma unroll
        for(int nf=0;nf<4;nf++)
          acc[mf][nf] = __builtin_amdgcn_mfma_f32_16x16x32_bf16(af[mf], bfv[nf], acc[mf][nf], 0,0,0);
    }
    __syncthreads();
  }

  if constexpr (KSPLIT == 1){
    #pragma unroll
    for(int nf=0;nf<4;nf++){
      int co = cobase + wn*64 + nf*16 + l15;
      float bv = bias[co];
      #pragma unroll
      for(int mf=0;mf<4;mf++){
        int m = wm*64 + mf*16 + 4*kg;
        int bp = (NBT>1) ? (m/LT) : 0;
        int ll = (NBT>1) ? (m%LT) : m;
        f32x4 a = acc[mf][nf];
        ushort4 o;
        o.x = f2bf(fmaxf(a[0]+bv,0.f));
        o.y = f2bf(fmaxf(a[1]+bv,0.f));
        o.z = f2bf(fmaxf(a[2]+bv,0.f));
        o.w = f2bf(fmaxf(a[3]+bv,0.f));
        size_t off = ((size_t)((b0+bp)*COUT + co))*LOUTP + 16 + l0 + ll;
        *(ushort4*)&actout[off] = o;
      }
    }
  } else {
    #pragma unroll
    for(int nf=0;nf<4;nf++){
      int co = cobase + wn*64 + nf*16 + l15;
      #pragma unroll
      for(int mf=0;mf<4;mf++){
        int mloc = wm*64 + mf*16 + 4*kg;
        int mglob = mt*128 + mloc;
        *(f32x4*)&partial[((size_t)(z*COUT + co))*MT + mglob] = acc[mf][nf];
      }
    }
  }
}

// ---------------- reduce K-split partials -> bf16 padded act ----------------
template<int COUT, int MT, int LOUT, int KS>
__global__ __launch_bounds__(256) void reduce_k(const float* __restrict__ partial,
    const float* __restrict__ bias, unsigned short* __restrict__ actout){
  int idx = blockIdx.x*256 + threadIdx.x;
  if(idx >= COUT*(MT/4)) return;
  int m4 = idx % (MT/4); int co = idx / (MT/4);
  int m = m4*4;
  float4 a = *(const float4*)&partial[(size_t)co*MT + m];
  #pragma unroll
  for(int zz=1; zz<KS; zz++){
    float4 b = *(const float4*)&partial[((size_t)(zz*COUT + co))*MT + m];
    a.x += b.x; a.y += b.y; a.z += b.z; a.w += b.w;
  }
  float bv = bias[co];
  int b_ = m / LOUT, l = m % LOUT;
  ushort4 o;
  o.x = f2bf(fmaxf(a.x+bv,0.f));
  o.y = f2bf(fmaxf(a.y+bv,0.f));
  o.z = f2bf(fmaxf(a.z+bv,0.f));
  o.w = f2bf(fmaxf(a.w+bv,0.f));
  *(ushort4*)&actout[((size_t)(b_*COUT + co))*(LOUT+32) + 16 + l] = o;
}

// ---------------- gather act4 -> hflatb bf16 [B][8192], pre-swizzled by batch ----------------
__global__ __launch_bounds__(256) void gather_k(const unsigned short* __restrict__ act4,
    unsigned short* __restrict__ hflatb){
  __shared__ unsigned short trans[8][260];
  int b = blockIdx.x >> 2, ct = blockIdx.x & 3;
  int c0 = ct*256;
  int tid = threadIdx.x;
  uint4 v = *(const uint4*)&act4[((size_t)(b*1024 + c0 + tid))*40 + 16];
  unsigned short* pv = (unsigned short*)&v;
  #pragma unroll
  for(int l=0;l<8;l++) trans[l][tid] = pv[l];
  __syncthreads();
  int l = tid>>5, cg_ = tid&31;
  uint4 o;
  unsigned short* po = (unsigned short*)&o;
  #pragma unroll
  for(int e=0;e<8;e++) po[e] = trans[l][cg_*8+e];
  int G = l*128 + ct*32 + cg_;
  *(uint4*)&hflatb[(size_t)b*8192 + (size_t)((G ^ (b&7))*8)] = o;
}

// ---------------- pack proj weights: [1024 n][8192 d] bf16 ----------------
__global__ __launch_bounds__(256) void packwproj_k(const float* __restrict__ phw,
    const float* __restrict__ pcw, unsigned short* __restrict__ wproj){
  int idx = blockIdx.x*256 + threadIdx.x;
  if(idx >= 1024*8192) return;
  int n = idx >> 13, d = idx & 8191;
  float v = (n < 512) ? phw[(size_t)n*8192 + d] : pcw[(size_t)(n-512)*8192 + d];
  wproj[idx] = f2bf(v);
}

// ---------------- pack LSTM weights: [2048 n][512 k] bf16, n = u*4+g ----------------
__global__ __launch_bounds__(256) void packwlstm_k(const float* __restrict__ whh,
    unsigned short* __restrict__ wpb){
  int idx = blockIdx.x*256 + threadIdx.x;
  if(idx >= 2048*512) return;
  int n = idx >> 9, k = idx & 511;
  int u = n >> 2, g = n & 3;
  wpb[idx] = f2bf(whh[(size_t)(g*512+u)*512 + k]);
}

// ---------------- pack E vectors (wave-parallel: one 512-row dot per wave) ----------------
__global__ __launch_bounds__(256) void pack_e2_k(const float* __restrict__ wih,
    const float* __restrict__ bih, const float* __restrict__ bhh,
    const float* __restrict__ embw, const float* __restrict__ embb,
    float* __restrict__ E0, float* __restrict__ E1, float* __restrict__ BX, float* __restrict__ B0){
  int row = blockIdx.x*4 + (threadIdx.x>>6);   // 512 blocks x 4 waves = 2048 rows
  int lane = threadIdx.x & 63;
  const float* wr = wih + (size_t)row*512;
  float e0=0.f, e1=0.f, bx=0.f;
  #pragma unroll
  for(int e=0;e<8;e++){
    int j = lane + 64*e;
    float wv = wr[j];
    e0 = fmaf(wv, embw[j*2+0], e0);
    e1 = fmaf(wv, embw[j*2+1], e1);
    bx = fmaf(wv, embb[j], bx);
  }
  #pragma unroll
  for(int off=32; off; off>>=1){
    e0 += __shfl_down(e0, off, 64);
    e1 += __shfl_down(e1, off, 64);
    bx += __shfl_down(bx, off, 64);
  }
  if(lane==0){
    int u = row & 511, g = row >> 9;
    float b0v = bih[row] + bhh[row];
    E0[u*4+g] = e0; E1[u*4+g] = e1; BX[u*4+g] = bx + b0v; B0[u*4+g] = b0v;
  }
}

// ---------------- projection via MFMA, K-split: grid 128 = 8 nt x 16 zk ----------------
__global__ __launch_bounds__(256,2) void projm2_k(
    const unsigned short* __restrict__ hflatb,
    const unsigned short* __restrict__ wproj,
    float* __restrict__ partial)      // [16 zk][1024 n][128 b]
{
  __shared__ __align__(16) char smem[2*(16384+16384)];
  char* Bb = smem;
  char* Ab = smem + 32768;
  int bid = blockIdx.x;
  int zk = bid & 15, nt = bid >> 4;
  int n0 = nt*128;
  int tid = threadIdx.x, lane = tid&63, wid = tid>>6;
  int wm = wid>>1, wn = wid&1;
  int l15 = lane&15, kg = lane>>4;

  auto STAGE = [&](int kc){
    int buf = kc&1;
    #pragma unroll
    for(int i=0;i<4;i++){
      int q = tid + i*256;
      int col = q>>3, j = q&7;
      const char* src = (const char*)wproj + (size_t)(n0+col)*16384
                        + (size_t)zk*1024 + kc*128 + ((j*16) ^ ((col&7)<<4));
      gld_lds16(src, Bb + buf*16384 + q*16);
    }
    #pragma unroll
    for(int i=0;i<4;i++){
      int q = tid + i*256;
      int row = q>>3, j = q&7;
      // hflatb is ALREADY pre-swizzled in global (gather_k) -> stage LINEARLY.
      const char* src = (const char*)hflatb + (size_t)row*16384
                        + (size_t)zk*1024 + kc*128 + j*16;
      gld_lds16(src, Ab + buf*16384 + q*16);
    }
  };

  const f32x4 vz = {0.f,0.f,0.f,0.f};
  f32x4 acc[4][4];
  #pragma unroll
  for(int i=0;i<4;i++)
    #pragma unroll
    for(int j=0;j<4;j++) acc[i][j] = vz;

  STAGE(0);
  __syncthreads();
  for(int kc=0;kc<8;kc++){
    if(kc<7) STAGE(kc+1);
    const char* Ac = Ab + (kc&1)*16384;
    const char* Bc = Bb + (kc&1)*16384;
    #pragma unroll
    for(int c=0;c<2;c++){
      bf16x8 af[4], bfv[4];
      #pragma unroll
      for(int mf=0;mf<4;mf++){
        int row = wm*64 + mf*16 + l15;
        af[mf] = *(const bf16x8*)(Ac + row*128 + ((c*64 + kg*16) ^ ((row&7)<<4)));
      }
      #pragma unroll
      for(int nf=0;nf<4;nf++){
        int col = wn*64 + nf*16 + l15;
        bfv[nf] = *(const bf16x8*)(Bc + col*128 + ((c*64 + kg*16) ^ ((col&7)<<4)));
      }
      #pragma unroll
      for(int mf=0;mf<4;mf++)
        #pragma unroll
        for(int nf=0;nf<4;nf++)
          acc[mf][nf] = __builtin_amdgcn_mfma_f32_16x16x32_bf16(af[mf], bfv[nf], acc[mf][nf], 0,0,0);
    }
    __syncthreads();
  }
  #pragma unroll
  for(int nf=0;nf<4;nf++){
    int n = n0 + wn*64 + nf*16 + l15;
    #pragma unroll
    for(int mf=0;mf<4;mf++){
      int m = wm*64 + mf*16 + kg*4;
      *(f32x4*)&partial[((size_t)zk*1024 + n)*128 + m] = acc[mf][nf];
    }
  }
}

// ---------------- reduce proj partials -> hbf0 (swizzled bf16) + cbuf ----------------
__global__ __launch_bounds__(256) void reduceproj_k(const float* __restrict__ partial,
    const float* __restrict__ phb, const float* __restrict__ pcb,
    unsigned short* __restrict__ hbf0, float* __restrict__ cbuf){
  int idx = blockIdx.x*256 + threadIdx.x;    // 32768 = 1024 n x 32 b-quads
  int n = idx >> 5; int b4 = (idx & 31)*4;
  const float* p = partial + (size_t)n*128 + b4;
  float4 a = *(const float4*)p;
  #pragma unroll
  for(int z=1; z<16; z++){
    float4 v = *(const float4*)(p + (size_t)z*131072);
    a.x+=v.x; a.y+=v.y; a.z+=v.z; a.w+=v.w;
  }
  float av[4] = {a.x, a.y, a.z, a.w};
  if(n < 512){
    float bv = phb[n];
    #pragma unroll
    for(int j=0;j<4;j++){
      int b = b4 + j;
      hbf0[(size_t)b*512 + (n ^ ((b&7)<<3))] = f2bf(av[j] + bv);
    }
  } else {
    float bv = pcb[n-512];
    #pragma unroll
    for(int j=0;j<4;j++){
      int b = b4 + j;
      cbuf[(size_t)b*512 + (n-512)] = av[j] + bv;
    }
  }
}

// ---------------- persistent LSTM v2: 256 blocks (bt=bid&7 -> XCD-local), custom per-bt barrier ----------------
__global__ __launch_bounds__(256) void lstm_pers2_k(
    const unsigned short* __restrict__ wpb,
    unsigned short* __restrict__ hbf0,
    unsigned short* __restrict__ hbf1,
    const float* __restrict__ cbuf,
    const float4* __restrict__ E0v, const float4* __restrict__ E1v,
    const float4* __restrict__ BXv, const float4* __restrict__ B0v,
    const float* __restrict__ lf0w, const float* __restrict__ lf0b,
    const float* __restrict__ uvw, const float* __restrict__ uvb,
    float* __restrict__ dout, unsigned* __restrict__ bar)
{
  __shared__ __align__(16) char W[65536];    // 64 cols x 1024 B (XOR-swizzled)
  __shared__ __align__(16) char A[16384];    // 16 rows x 1024 B (XOR-swizzled)
  __shared__ __align__(16) float gates[16][68];
  __shared__ float red0[16][17], red1[16][17];
  __shared__ float lf_s[16], uv_s[16];

  int bid = blockIdx.x;
  int bt = bid & 7, ut = bid >> 3;     // same-bt blocks land on same XCD (perf only)
  int b0 = bt*16, n0 = ut*64;
  int tid = threadIdx.x, lane = tid&63, wn = tid>>6;
  int l15 = lane&15, kg = lane>>4;

  // one-time: W slice -> LDS
  #pragma unroll
  for(int i=0;i<16;i++){
    int q = i*256 + tid;
    int col = q>>6, j = q&63;
    const char* src = (const char*)wpb + (size_t)(n0+col)*1024 + ((j*16) ^ ((col&7)<<4));
    gld_lds16(src, W + q*16);
  }
  // per-thread persistent state
  int eb = tid & 15, eu = tid >> 4;          // epilogue (b, u_local)
  int ug = ut*16 + eu;
  float4 e0r = E0v[ug], e1r = E1v[ug], bxr = BXv[ug], b0r = B0v[ug];
  float c_reg = cbuf[(size_t)(b0+eb)*512 + ug];
  float lf0b_v = lf0b[0], uvb_v = uvb[0];
  int hb = tid & 15, hs = tid >> 4;
  int c = wn*16 + l15;
  int aswz = (l15&7)<<4, bswz = (c&7)<<4;
  const f32x4 vz = {0.f,0.f,0.f,0.f};

  for(int t=0; t<=NSTEPS; t++){
    // wait for all 32 blocks of this bt to finish step t-1
    if(t > 0){
      if(tid == 0){
        while(__hip_atomic_load(&bar[bt], __ATOMIC_RELAXED, __HIP_MEMORY_SCOPE_AGENT) < 32u*(unsigned)t)
          __builtin_amdgcn_s_sleep(1);
      }
      __syncthreads();
      __threadfence();   // acquire: invalidate stale h lines
    }
    // stage h_t (16 rows x 1KB) into A
    const unsigned short* hp = (t&1) ? hbf1 : hbf0;
    #pragma unroll
    for(int i=0;i<4;i++){
      int q = i*256 + tid;
      gld_lds16((const char*)hp + (size_t)b0*1024 + q*16, A + q*16);
    }
    asm volatile("s_waitcnt vmcnt(0)");
    __syncthreads();

    // heads for output t-1
    if(t > 0){
      float p0 = 0.f, p1 = 0.f;
      #pragma unroll
      for(int j=0;j<4;j++){
        bf16x8 hv = *(const bf16x8*)(A + hb*1024 + ((hs*64 + j*16) ^ ((hb&7)<<4)));
        #pragma unroll
        for(int e=0;e<8;e++){
          float h = bf2f((unsigned short)hv[e]);
          int k = hs*32 + j*8 + e;
          p0 = fmaf(h, lf0w[k], p0);
          p1 = fmaf(h, uvw[k], p1);
        }
      }
      red0[hs][hb] = p0; red1[hs][hb] = p1;
    }

    // gates GEMM from resident W
    if(t < NSTEPS){
      f32x4 acc = vz;
      #pragma unroll
      for(int ks=0; ks<16; ks++){
        int kb = ks*64 + kg*16;
        bf16x8 af = *(const bf16x8*)(A + l15*1024 + (kb ^ aswz));
        bf16x8 bf = *(const bf16x8*)(W + c*1024 + (kb ^ bswz));
        acc = __builtin_amdgcn_mfma_f32_16x16x32_bf16(af, bf, acc, 0,0,0);
      }
      #pragma unroll
      for(int j=0;j<4;j++) gates[kg*4+j][c] = acc[j];
    }
    __syncthreads();

    if(t > 0 && tid < 16){
      float a0=0.f, a1=0.f;
      #pragma unroll
      for(int s2=0;s2<16;s2++){ a0 += red0[s2][tid]; a1 += red1[s2][tid]; }
      a0 += lf0b_v;
      a1 = sigm(a1 + uvb_v);
      lf_s[tid] = a0; uv_s[tid] = a1;
      if(ut == 0){
        dout[(size_t)(b0+tid)*(2*NSTEPS) + (t-1)*2 + 0] = a0;
        dout[(size_t)(b0+tid)*(2*NSTEPS) + (t-1)*2 + 1] = a1;
      }
    }
    __syncthreads();

    if(t == NSTEPS) break;

    unsigned short* hn = (t&1) ? hbf0 : hbf1;
    {
      float4 g4 = *(const float4*)&gates[eb][eu*4];
      float4 xp;
      if(t == 0){
        xp = make_float4(b0r.x, b0r.y, b0r.z, b0r.w);
      } else {
        float lf = lf_s[eb], uvv = uv_s[eb];
        xp.x = fmaf(lf, e0r.x, fmaf(uvv, e1r.x, bxr.x));
        xp.y = fmaf(lf, e0r.y, fmaf(uvv, e1r.y, bxr.y));
        xp.z = fmaf(lf, e0r.z, fmaf(uvv, e1r.z, bxr.z));
        xp.w = fmaf(lf, e0r.w, fmaf(uvv, e1r.w, bxr.w));
      }
      float gi = sigm(g4.x + xp.x);
      float gf = sigm(g4.y + xp.y);
      float gg = tanhf(g4.z + xp.z);
      float go = sigm(g4.w + xp.w);
      c_reg = fmaf(gf, c_reg, gi*gg);
      float hnv = go * tanhf(c_reg);
      hn[(size_t)(b0+eb)*512 + (ug ^ ((eb&7)<<3))] = f2bf(hnv);
    }
    // release: every thread fences its store, then one arrival per block
    __threadfence();
    __syncthreads();
    if(tid == 0)
      __hip_atomic_fetch_add(&bar[bt], 1u, __ATOMIC_RELAXED, __HIP_MEMORY_SCOPE_AGENT);
  }
}

extern "C" void kernel_launch(void* const* d_in, const int* in_sizes, int n_in,
                              void* d_out, int out_size, void* d_ws, size_t ws_size,
                              hipStream_t stream) {
  const float* x    = (const float*)d_in[0];
  const float* cw0  = (const float*)d_in[2];  const float* cb0 = (const float*)d_in[3];
  const float* cw1  = (const float*)d_in[4];  const float* cb1 = (const float*)d_in[5];
  const float* cw2  = (const float*)d_in[6];  const float* cb2 = (const float*)d_in[7];
  const float* cw3  = (const float*)d_in[8];  const float* cb3 = (const float*)d_in[9];
  const float* cw4  = (const float*)d_in[10]; const float* cb4 = (const float*)d_in[11];
  const float* phw  = (const float*)d_in[12]; const float* phb = (const float*)d_in[13];
  const float* pcw  = (const float*)d_in[14]; const float* pcb = (const float*)d_in[15];
  const float* wih  = (const float*)d_in[16]; const float* whh = (const float*)d_in[17];
  const float* bih  = (const float*)d_in[18]; const float* bhh = (const float*)d_in[19];
  const float* lf0w = (const float*)d_in[20]; const float* lf0b = (const float*)d_in[21];
  const float* uvw  = (const float*)d_in[22]; const float* uvb  = (const float*)d_in[23];
  const float* embw = (const float*)d_in[24]; const float* embb = (const float*)d_in[25];
  float* dout = (float*)d_out;

  float* ws = (float*)d_ws;
  unsigned short* act0 = (unsigned short*)ws;
  unsigned short* act2 = (unsigned short*)ws;
  unsigned short* act4 = (unsigned short*)ws;
  float*          part = ws + 2883584;                      // conv partials
  unsigned short* wproj= (unsigned short*)(ws + 2883584);   // proj weights (after convs)
  unsigned short* hflatb=(unsigned short*)(ws + 7077888);   // 2 MB
  unsigned short* act1 = (unsigned short*)(ws + 8519680);
  unsigned short* act3 = (unsigned short*)(ws + 8519680);
  float*          ppart= ws + 8519680;                      // proj partials (8 MB, region B)
  unsigned short* wpk1 = (unsigned short*)(ws + 12976128);
  unsigned short* wpk2 = wpk1 + 262144;
  unsigned short* wpk3 = wpk2 + 1048576;
  unsigned short* wpk4 = wpk3 + 4194304;
  unsigned short* wpb = (unsigned short*)(ws + 24117248);
  float*  E0  = ws + 24641536;
  float*  E1  = E0 + 2048;
  float*  BX  = E1 + 2048;
  float*  B0  = BX + 2048;
  float*  cb  = ws + 24649728;
  unsigned short* hbf0 = (unsigned short*)(ws + 24715264);
  unsigned short* hbf1 = (unsigned short*)(ws + 24748032);
  unsigned*       bar  = (unsigned*)(ws + 24781312);        // 8 counters

  // ---- packs & pads ----
  packw_k<<<(128*64*32+255)/256, 256, 0, stream>>>(cw1, wpk1, 128*64*32);
  packw_k<<<(256*128*32+255)/256, 256, 0, stream>>>(cw2, wpk2, 256*128*32);
  packw_k<<<(512*256*32+255)/256, 256, 0, stream>>>(cw3, wpk3, 512*256*32);
  packw_k<<<(1024*512*32+255)/256, 256, 0, stream>>>(cw4, wpk4, 1024*512*32);
  packwlstm_k<<<4096, 256, 0, stream>>>(whh, wpb);
  pack_e2_k<<<512, 256, 0, stream>>>(wih, bih, bhh, embw, embb, E0, E1, BX, B0);
  zpad_k<<<(128*64*8+255)/256, 256, 0, stream>>>(act0, 128*64, 2048);
  zpad_k<<<(128*128*8+255)/256, 256, 0, stream>>>(act1, 128*128, 512);
  hipMemsetAsync((void*)bar, 0, 8*sizeof(unsigned), stream);

  // ---- conv stack ----
  conv0_k<<<1024, 256, 0, stream>>>(x, cw0, cb0, act0);
  conv_mfma_k<64,2048,512,128,1,128,1><<<512, 256, 0, stream>>>(act0, wpk1, cb1, act1, nullptr);
  zpad_k<<<(128*256*8+255)/256, 256, 0, stream>>>(act2, 128*256, 128);
  conv_mfma_k<128,512,128,128,1,256,1><<<256, 256, 0, stream>>>(act1, wpk2, cb2, act2, nullptr);
  zpad_k<<<(128*512*8+255)/256, 256, 0, stream>>>(act3, 128*512, 32);
  conv_mfma_k<256,128,32,32,4,512,2><<<256, 256, 0, stream>>>(act2, wpk3, cb3, nullptr, part);
  reduce_k<512,4096,32,2><<<2048, 256, 0, stream>>>(part, cb3, act3);
  conv_mfma_k<512,32,8,8,16,1024,4><<<256, 256, 0, stream>>>(act3, wpk4, cb4, nullptr, part);
  reduce_k<1024,1024,8,4><<<1024, 256, 0, stream>>>(part, cb4, act4);

  // ---- proj (MFMA, K-split) ----
  packwproj_k<<<32768, 256, 0, stream>>>(phw, pcw, wproj);
  gather_k<<<512, 256, 0, stream>>>(act4, hflatb);
  projm2_k<<<128, 256, 0, stream>>>(hflatb, wproj, ppart);
  reduceproj_k<<<128, 256, 0, stream>>>(ppart, phb, pcb, hbf0, cb);

  // ---- LSTM (persistent, custom per-bt barrier) ----
  {
    void* args[] = {
      (void*)&wpb, (void*)&hbf0, (void*)&hbf1, (void*)&cb,
      (void*)&E0, (void*)&E1, (void*)&BX, (void*)&B0,
      (void*)&lf0w, (void*)&lf0b, (void*)&uvw, (void*)&uvb, (void*)&dout, (void*)&bar
    };
    hipLaunchCooperativeKernel((void*)lstm_pers2_k, dim3(256), dim3(256), args, 0, stream);
  }
}

// Round 9
// 1308.181 us; speedup vs baseline: 6.8626x; 6.8626x over previous
//
#include <hip/hip_runtime.h>

#define NSTEPS 200

typedef __attribute__((ext_vector_type(8))) short bf16x8;
typedef __attribute__((ext_vector_type(4))) float f32x4;

__device__ __forceinline__ float sigm(float x){ return 1.0f/(1.0f + __expf(-x)); }

__device__ __forceinline__ unsigned short f2bf(float f){
  unsigned int u = __float_as_uint(f);
  u = u + 0x7FFFu + ((u>>16)&1u);
  return (unsigned short)(u>>16);
}
__device__ __forceinline__ float bf2f(unsigned short s){
  return __uint_as_float(((unsigned int)s)<<16);
}

__device__ __forceinline__ void gld_lds16(const void* g, void* l){
  __builtin_amdgcn_global_load_lds(
    (const __attribute__((address_space(1))) unsigned int*)g,
    (__attribute__((address_space(3))) unsigned int*)l, 16, 0, 0);
}

// ---------------- zero row pads of a padded bf16 activation buffer ----------------
__global__ __launch_bounds__(256) void zpad_k(unsigned short* __restrict__ p, int nrows, int L){
  int idx = blockIdx.x*256 + threadIdx.x;
  if(idx >= nrows*8) return;
  int row = idx>>3; int j = idx&7;
  int off = (j<4) ? j*4 : (16 + L + (j-4)*4);
  ushort4 z; z.x=0; z.y=0; z.z=0; z.w=0;
  *(ushort4*)&p[(size_t)row*(L+32) + off] = z;
}

// ---------------- pack conv weights: fp32 [CO][CI][31] -> bf16 [CO][CI*32] (slot0=0) ----------------
__global__ __launch_bounds__(256) void packw_k(const float* __restrict__ w, unsigned short* __restrict__ wpk, int total){
  int idx = blockIdx.x*256 + threadIdx.x;
  if(idx >= total) return;
  int k = idx & 31; int r = idx >> 5;
  wpk[idx] = (k >= 1) ? f2bf(w[(size_t)r*31 + (k-1)]) : (unsigned short)0;
}

// ---------------- conv0: Cin=1, Cout=64, L 8192->2048, fp32 VALU, bf16 padded out ----------------
__global__ __launch_bounds__(256) void conv0_k(const float* __restrict__ x,
    const float* __restrict__ w, const float* __restrict__ bias, unsigned short* __restrict__ act0){
  __shared__ float xl[1056];
  __shared__ float wl[64*31];
  __shared__ float bl[64];
  int b = blockIdx.x >> 3; int lt = blockIdx.x & 7;
  int l0 = lt*256; int tid = threadIdx.x;
  for(int i=tid;i<1056;i+=256){
    int g = 4*l0 - 15 + i;
    xl[i] = (g>=0 && g<8192) ? x[(size_t)b*8192 + g] : 0.f;
  }
  for(int i=tid;i<1984;i+=256) wl[i] = w[i];
  if(tid<64) bl[tid]=bias[tid];
  __syncthreads();
  float xr[31];
  #pragma unroll
  for(int j=0;j<31;j++) xr[j] = xl[4*tid + j];
  size_t obase = ((size_t)b*64)*2080 + 16 + l0 + tid;
  for(int co=0;co<64;co++){
    float acc = bl[co];
    #pragma unroll
    for(int j=0;j<31;j++) acc = fmaf(wl[co*31+j], xr[j], acc);
    act0[obase + (size_t)co*2080] = f2bf(fmaxf(acc,0.f));
  }
}

// ---------------- generic MFMA conv (as GEMM M=(b,l), N=co, K=ci*32+tap) ----------------
template<int CIN, int LIN, int LOUT, int LT, int NBT, int COUT, int KSPLIT>
__global__ __launch_bounds__(256,3) void conv_mfma_k(
    const unsigned short* __restrict__ actin,
    const unsigned short* __restrict__ wpk,
    const float* __restrict__ bias,
    unsigned short* __restrict__ actout,
    float* __restrict__ partial)
{
  constexpr int LINP  = LIN + 32;
  constexpr int LOUTP = LOUT + 32;
  constexpr int SPANB = 8*LT + 64;
  constexpr int SC    = SPANB/16;
  constexpr int CA    = 2*NBT*SC;
  static_assert(CA <= 256, "CA");
  constexpr int ASZ   = CA*16;
  constexpr int BSZ   = 16384;
  constexpr int MT    = 128*LOUT;
  constexpr int MTILES= MT/128;
  constexpr int NT    = COUT/128;
  constexpr int NSTEP = CIN/2/KSPLIT;
  constexpr int GRID  = MTILES*NT*KSPLIT;
  static_assert(GRID % 8 == 0, "grid%8");
  __shared__ __align__(16) char smem[2*(BSZ+ASZ)];
  char* Bb = smem;
  char* Ab = smem + 2*BSZ;

  // XCD-aware swizzle: consecutive LOGICAL bids (sharing the (nt,z) weight
  // slice) land on ONE XCD.
  int bid = (blockIdx.x & 7)*(GRID/8) + (blockIdx.x >> 3);
  int mt = bid % MTILES; bid /= MTILES;
  int nt = bid % NT;     int z = bid / NT;
  int b0 = (mt*128)/LOUT;
  int l0 = (mt*128)%LOUT;
  int cobase = nt*128;
  int s0 = z*NSTEP, s1 = s0 + NSTEP;

  int tid = threadIdx.x; int lane = tid&63; int wid = tid>>6;
  int wm = wid>>1, wn = wid&1;
  int l15 = lane&15, kg = lane>>4;

  int aq_c=0, aq_b=0, aq_j=0; bool a_act = tid < CA;
  { int q = tid; aq_c = q/(NBT*SC); int r = q%(NBT*SC); aq_b = r/SC; aq_j = r%SC; }

  auto STAGE = [&](int st){
    int buf = st&1;
    #pragma unroll
    for(int i=0;i<4;i++){
      int qb = tid + i*256;
      int col = qb>>3; int j = qb&7;
      const char* src = (const char*)wpk + (size_t)(cobase+col)*(CIN*64) + (size_t)st*128
                        + ((j*16) ^ ((col&7)<<4));
      gld_lds16(src, Bb + buf*BSZ + qb*16);
    }
    if(a_act){
      int ci = 2*st + aq_c;
      const char* src = (const char*)actin
          + 2*((size_t)((b0+aq_b)*CIN + ci)*LINP + 4*l0) + aq_j*16;
      gld_lds16(src, Ab + buf*ASZ + tid*16);
    }
  };

  int abyte[2][4], bbyte[2][4];
  #pragma unroll
  for(int c=0;c<2;c++){
    #pragma unroll
    for(int mf=0;mf<4;mf++){
      int r = wm*64 + mf*16 + l15;
      int bp = (NBT>1) ? (r/LT) : 0;
      int ll = (NBT>1) ? (r%LT) : r;
      abyte[c][mf] = (c*NBT + bp)*SPANB + 8*ll + 16*kg;
    }
    #pragma unroll
    for(int nf=0;nf<4;nf++){
      int col = wn*64 + nf*16 + l15;
      bbyte[c][nf] = col*128 + ((c*64 + 16*kg) ^ ((col&7)<<4));
    }
  }

  const f32x4 vz = {0.f,0.f,0.f,0.f};
  f32x4 acc[4][4];
  #pragma unroll
  for(int i=0;i<4;i++)
    #pragma unroll
    for(int j=0;j<4;j++) acc[i][j] = vz;

  STAGE(s0);
  __syncthreads();
  for(int s=s0;s<s1;s++){
    if(s+1<s1) STAGE(s+1);
    const char* Ac = Ab + (s&1)*ASZ;
    const char* Bc = Bb + (s&1)*BSZ;
    #pragma unroll
    for(int c=0;c<2;c++){
      bf16x8 af[4], bfv[4];
      #pragma unroll
      for(int mf=0;mf<4;mf++){
        const char* ap = Ac + abyte[c][mf];
        union { unsigned long long u[2]; bf16x8 v; } t;
        t.u[0] = *(const unsigned long long*)ap;
        t.u[1] = *(const unsigned long long*)(ap+8);
        af[mf] = t.v;
      }
      #pragma unroll
      for(int nf=0;nf<4;nf++) bfv[nf] = *(const bf16x8*)(Bc + bbyte[c][nf]);
      #pragma unroll
      for(int mf=0;mf<4;mf++)
        #pragma unroll
        for(int nf=0;nf<4;nf++)
          acc[mf][nf] = __builtin_amdgcn_mfma_f32_16x16x32_bf16(af[mf], bfv[nf], acc[mf][nf], 0,0,0);
    }
    __syncthreads();
  }

  if constexpr (KSPLIT == 1){
    #pragma unroll
    for(int nf=0;nf<4;nf++){
      int co = cobase + wn*64 + nf*16 + l15;
      float bv = bias[co];
      #pragma unroll
      for(int mf=0;mf<4;mf++){
        int m = wm*64 + mf*16 + 4*kg;
        int bp = (NBT>1) ? (m/LT) : 0;
        int ll = (NBT>1) ? (m%LT) : m;
        f32x4 a = acc[mf][nf];
        ushort4 o;
        o.x = f2bf(fmaxf(a[0]+bv,0.f));
        o.y = f2bf(fmaxf(a[1]+bv,0.f));
        o.z = f2bf(fmaxf(a[2]+bv,0.f));
        o.w = f2bf(fmaxf(a[3]+bv,0.f));
        size_t off = ((size_t)((b0+bp)*COUT + co))*LOUTP + 16 + l0 + ll;
        *(ushort4*)&actout[off] = o;
      }
    }
  } else {
    #pragma unroll
    for(int nf=0;nf<4;nf++){
      int co = cobase + wn*64 + nf*16 + l15;
      #pragma unroll
      for(int mf=0;mf<4;mf++){
        int mloc = wm*64 + mf*16 + 4*kg;
        int mglob = mt*128 + mloc;
        *(f32x4*)&partial[((size_t)(z*COUT + co))*MT + mglob] = acc[mf][nf];
      }
    }
  }
}

// ---------------- reduce K-split partials -> bf16 padded act ----------------
template<int COUT, int MT, int LOUT, int KS>
__global__ __launch_bounds__(256) void reduce_k(const float* __restrict__ partial,
    const float* __restrict__ bias, unsigned short* __restrict__ actout){
  int idx = blockIdx.x*256 + threadIdx.x;
  if(idx >= COUT*(MT/4)) return;
  int m4 = idx % (MT/4); int co = idx / (MT/4);
  int m = m4*4;
  float4 a = *(const float4*)&partial[(size_t)co*MT + m];
  #pragma unroll
  for(int zz=1; zz<KS; zz++){
    float4 b = *(const float4*)&partial[((size_t)(zz*COUT + co))*MT + m];
    a.x += b.x; a.y += b.y; a.z += b.z; a.w += b.w;
  }
  float bv = bias[co];
  int b_ = m / LOUT, l = m % LOUT;
  ushort4 o;
  o.x = f2bf(fmaxf(a.x+bv,0.f));
  o.y = f2bf(fmaxf(a.y+bv,0.f));
  o.z = f2bf(fmaxf(a.z+bv,0.f));
  o.w = f2bf(fmaxf(a.w+bv,0.f));
  *(ushort4*)&actout[((size_t)(b_*COUT + co))*(LOUT+32) + 16 + l] = o;
}

// ---------------- gather act4 -> hflatb bf16 [B][8192], pre-swizzled by batch ----------------
__global__ __launch_bounds__(256) void gather_k(const unsigned short* __restrict__ act4,
    unsigned short* __restrict__ hflatb){
  __shared__ unsigned short trans[8][260];
  int b = blockIdx.x >> 2, ct = blockIdx.x & 3;
  int c0 = ct*256;
  int tid = threadIdx.x;
  uint4 v = *(const uint4*)&act4[((size_t)(b*1024 + c0 + tid))*40 + 16];
  unsigned short* pv = (unsigned short*)&v;
  #pragma unroll
  for(int l=0;l<8;l++) trans[l][tid] = pv[l];
  __syncthreads();
  int l = tid>>5, cg_ = tid&31;
  uint4 o;
  unsigned short* po = (unsigned short*)&o;
  #pragma unroll
  for(int e=0;e<8;e++) po[e] = trans[l][cg_*8+e];
  int G = l*128 + ct*32 + cg_;
  *(uint4*)&hflatb[(size_t)b*8192 + (size_t)((G ^ (b&7))*8)] = o;
}

// ---------------- pack proj weights: [1024 n][8192 d] bf16 ----------------
__global__ __launch_bounds__(256) void packwproj_k(const float* __restrict__ phw,
    const float* __restrict__ pcw, unsigned short* __restrict__ wproj){
  int idx = blockIdx.x*256 + threadIdx.x;
  if(idx >= 1024*8192) return;
  int n = idx >> 13, d = idx & 8191;
  float v = (n < 512) ? phw[(size_t)n*8192 + d] : pcw[(size_t)(n-512)*8192 + d];
  wproj[idx] = f2bf(v);
}

// ---------------- pack LSTM weights: [2048 n][512 k] bf16, n = u*4+g ----------------
__global__ __launch_bounds__(256) void packwlstm_k(const float* __restrict__ whh,
    unsigned short* __restrict__ wpb){
  int idx = blockIdx.x*256 + threadIdx.x;
  if(idx >= 2048*512) return;
  int n = idx >> 9, k = idx & 511;
  int u = n >> 2, g = n & 3;
  wpb[idx] = f2bf(whh[(size_t)(g*512+u)*512 + k]);
}

// ---------------- pack E vectors (wave-parallel) ----------------
__global__ __launch_bounds__(256) void pack_e2_k(const float* __restrict__ wih,
    const float* __restrict__ bih, const float* __restrict__ bhh,
    const float* __restrict__ embw, const float* __restrict__ embb,
    float* __restrict__ E0, float* __restrict__ E1, float* __restrict__ BX, float* __restrict__ B0){
  int row = blockIdx.x*4 + (threadIdx.x>>6);
  int lane = threadIdx.x & 63;
  const float* wr = wih + (size_t)row*512;
  float e0=0.f, e1=0.f, bx=0.f;
  #pragma unroll
  for(int e=0;e<8;e++){
    int j = lane + 64*e;
    float wv = wr[j];
    e0 = fmaf(wv, embw[j*2+0], e0);
    e1 = fmaf(wv, embw[j*2+1], e1);
    bx = fmaf(wv, embb[j], bx);
  }
  #pragma unroll
  for(int off=32; off; off>>=1){
    e0 += __shfl_down(e0, off, 64);
    e1 += __shfl_down(e1, off, 64);
    bx += __shfl_down(bx, off, 64);
  }
  if(lane==0){
    int u = row & 511, g = row >> 9;
    float b0v = bih[row] + bhh[row];
    E0[u*4+g] = e0; E1[u*4+g] = e1; BX[u*4+g] = bx + b0v; B0[u*4+g] = b0v;
  }
}

// ---------------- projection via MFMA, K-split: grid 128 = 8 nt x 16 zk ----------------
__global__ __launch_bounds__(256,2) void projm2_k(
    const unsigned short* __restrict__ hflatb,
    const unsigned short* __restrict__ wproj,
    float* __restrict__ partial)      // [16 zk][1024 n][128 b]
{
  __shared__ __align__(16) char smem[2*(16384+16384)];
  char* Bb = smem;
  char* Ab = smem + 32768;
  int bid = blockIdx.x;
  int zk = bid & 15, nt = bid >> 4;
  int n0 = nt*128;
  int tid = threadIdx.x, lane = tid&63, wid = tid>>6;
  int wm = wid>>1, wn = wid&1;
  int l15 = lane&15, kg = lane>>4;

  auto STAGE = [&](int kc){
    int buf = kc&1;
    #pragma unroll
    for(int i=0;i<4;i++){
      int q = tid + i*256;
      int col = q>>3, j = q&7;
      const char* src = (const char*)wproj + (size_t)(n0+col)*16384
                        + (size_t)zk*1024 + kc*128 + ((j*16) ^ ((col&7)<<4));
      gld_lds16(src, Bb + buf*16384 + q*16);
    }
    #pragma unroll
    for(int i=0;i<4;i++){
      int q = tid + i*256;
      int row = q>>3, j = q&7;
      // hflatb is ALREADY pre-swizzled in global (gather_k) -> stage LINEARLY.
      const char* src = (const char*)hflatb + (size_t)row*16384
                        + (size_t)zk*1024 + kc*128 + j*16;
      gld_lds16(src, Ab + buf*16384 + q*16);
    }
  };

  const f32x4 vz = {0.f,0.f,0.f,0.f};
  f32x4 acc[4][4];
  #pragma unroll
  for(int i=0;i<4;i++)
    #pragma unroll
    for(int j=0;j<4;j++) acc[i][j] = vz;

  STAGE(0);
  __syncthreads();
  for(int kc=0;kc<8;kc++){
    if(kc<7) STAGE(kc+1);
    const char* Ac = Ab + (kc&1)*16384;
    const char* Bc = Bb + (kc&1)*16384;
    #pragma unroll
    for(int c=0;c<2;c++){
      bf16x8 af[4], bfv[4];
      #pragma unroll
      for(int mf=0;mf<4;mf++){
        int row = wm*64 + mf*16 + l15;
        af[mf] = *(const bf16x8*)(Ac + row*128 + ((c*64 + kg*16) ^ ((row&7)<<4)));
      }
      #pragma unroll
      for(int nf=0;nf<4;nf++){
        int col = wn*64 + nf*16 + l15;
        bfv[nf] = *(const bf16x8*)(Bc + col*128 + ((c*64 + kg*16) ^ ((col&7)<<4)));
      }
      #pragma unroll
      for(int mf=0;mf<4;mf++)
        #pragma unroll
        for(int nf=0;nf<4;nf++)
          acc[mf][nf] = __builtin_amdgcn_mfma_f32_16x16x32_bf16(af[mf], bfv[nf], acc[mf][nf], 0,0,0);
    }
    __syncthreads();
  }
  #pragma unroll
  for(int nf=0;nf<4;nf++){
    int n = n0 + wn*64 + nf*16 + l15;
    #pragma unroll
    for(int mf=0;mf<4;mf++){
      int m = wm*64 + mf*16 + kg*4;
      *(f32x4*)&partial[((size_t)zk*1024 + n)*128 + m] = acc[mf][nf];
    }
  }
}

// ---------------- reduce proj partials -> hbf0 (swizzled bf16) + cbuf ----------------
__global__ __launch_bounds__(256) void reduceproj_k(const float* __restrict__ partial,
    const float* __restrict__ phb, const float* __restrict__ pcb,
    unsigned short* __restrict__ hbf0, float* __restrict__ cbuf){
  int idx = blockIdx.x*256 + threadIdx.x;    // 32768 = 1024 n x 32 b-quads
  int n = idx >> 5; int b4 = (idx & 31)*4;
  const float* p = partial + (size_t)n*128 + b4;
  float4 a = *(const float4*)p;
  #pragma unroll
  for(int z=1; z<16; z++){
    float4 v = *(const float4*)(p + (size_t)z*131072);
    a.x+=v.x; a.y+=v.y; a.z+=v.z; a.w+=v.w;
  }
  float av[4] = {a.x, a.y, a.z, a.w};
  if(n < 512){
    float bv = phb[n];
    #pragma unroll
    for(int j=0;j<4;j++){
      int b = b4 + j;
      hbf0[(size_t)b*512 + (n ^ ((b&7)<<3))] = f2bf(av[j] + bv);
    }
  } else {
    float bv = pcb[n-512];
    #pragma unroll
    for(int j=0;j<4;j++){
      int b = b4 + j;
      cbuf[(size_t)b*512 + (n-512)] = av[j] + bv;
    }
  }
}

// ---------------- LSTM step v4: single-phase staging, 256 blocks (8 bt x 32 ut) ----------------
__global__ __launch_bounds__(256) void lstm4_k(
    const unsigned short* __restrict__ hbfprev,
    unsigned short* __restrict__ hbfnext,
    float* __restrict__ cbuf,
    const unsigned short* __restrict__ wpb,
    const float4* __restrict__ E0v, const float4* __restrict__ E1v,
    const float4* __restrict__ BXv, const float4* __restrict__ B0v,
    const float* __restrict__ lf0w, const float* __restrict__ lf0b,
    const float* __restrict__ uvw, const float* __restrict__ uvb,
    float* __restrict__ dout, int t)
{
  __shared__ __align__(16) char W[65536];    // 64 cols x 1024 B (XOR-swizzled)
  __shared__ __align__(16) char A[16384];    // 16 rows x 1024 B (XOR-swizzled)
  __shared__ __align__(16) float gates[16][68];
  __shared__ float red0[16][17], red1[16][17];
  __shared__ float lf_s[16], uv_s[16];

  int bid = blockIdx.x;
  int ut = bid & 31, bt = bid >> 5;
  int b0 = bt*16, n0 = ut*64;
  int tid = threadIdx.x, lane = tid&63, wn = tid>>6;
  int l15 = lane&15, kg = lane>>4;

  // single-phase staging: issue ALL loads, one wait, one barrier
  #pragma unroll
  for(int i=0;i<16;i++){
    int q = i*256 + tid;
    int col = q>>6, j = q&63;
    const char* src = (const char*)wpb + (size_t)(n0+col)*1024 + ((j*16) ^ ((col&7)<<4));
    gld_lds16(src, W + q*16);
  }
  #pragma unroll
  for(int i=0;i<4;i++){
    int q = i*256 + tid;
    gld_lds16((const char*)hbfprev + (size_t)b0*1024 + q*16, A + q*16);
  }
  asm volatile("s_waitcnt vmcnt(0)");
  __syncthreads();

  // gates GEMM: one 16-col tile per wave, K=512 in 16 MFMAs
  const f32x4 vz = {0.f,0.f,0.f,0.f};
  f32x4 acc = vz;
  int c = wn*16 + l15;
  int aswz = (l15&7)<<4, bswz = (c&7)<<4;
  #pragma unroll
  for(int ks=0; ks<16; ks++){
    int kb = ks*64 + kg*16;
    bf16x8 af = *(const bf16x8*)(A + l15*1024 + (kb ^ aswz));
    bf16x8 bf = *(const bf16x8*)(W + c*1024 + (kb ^ bswz));
    acc = __builtin_amdgcn_mfma_f32_16x16x32_bf16(af, bf, acc, 0,0,0);
  }
  #pragma unroll
  for(int j=0;j<4;j++) gates[kg*4+j][c] = acc[j];

  // heads for output t-1 (from staged h_prev)
  int hb = tid & 15, hs = tid >> 4;
  if(t > 0){
    float p0 = 0.f, p1 = 0.f;
    #pragma unroll
    for(int j=0;j<4;j++){
      bf16x8 hv = *(const bf16x8*)(A + hb*1024 + ((hs*64 + j*16) ^ ((hb&7)<<4)));
      #pragma unroll
      for(int e=0;e<8;e++){
        float h = bf2f((unsigned short)hv[e]);
        int k = hs*32 + j*8 + e;
        p0 = fmaf(h, lf0w[k], p0);
        p1 = fmaf(h, uvw[k], p1);
      }
    }
    red0[hs][hb] = p0; red1[hs][hb] = p1;
  }
  __syncthreads();
  if(t > 0 && tid < 16){
    float a0=0.f, a1=0.f;
    #pragma unroll
    for(int s2=0;s2<16;s2++){ a0 += red0[s2][tid]; a1 += red1[s2][tid]; }
    a0 += lf0b[0];
    a1 = sigm(a1 + uvb[0]);
    lf_s[tid] = a0; uv_s[tid] = a1;
    if(ut == 0){
      dout[(size_t)(b0+tid)*(2*NSTEPS) + (t-1)*2 + 0] = a0;
      dout[(size_t)(b0+tid)*(2*NSTEPS) + (t-1)*2 + 1] = a1;
    }
  }
  __syncthreads();

  // epilogue: one (b, u) per thread: 16 b x 16 u
  {
    int b = tid & 15, ul = tid >> 4;
    int u = ut*16 + ul;
    float4 g4 = *(const float4*)&gates[b][ul*4];
    float4 xp;
    if(t == 0){
      xp = B0v[u];
    } else {
      float lf = lf_s[b], uvv = uv_s[b];
      float4 e0 = E0v[u], e1 = E1v[u], bx = BXv[u];
      xp.x = fmaf(lf, e0.x, fmaf(uvv, e1.x, bx.x));
      xp.y = fmaf(lf, e0.y, fmaf(uvv, e1.y, bx.y));
      xp.z = fmaf(lf, e0.z, fmaf(uvv, e1.z, bx.z));
      xp.w = fmaf(lf, e0.w, fmaf(uvv, e1.w, bx.w));
    }
    float gi = sigm(g4.x + xp.x);
    float gf = sigm(g4.y + xp.y);
    float gg = tanhf(g4.z + xp.z);
    float go = sigm(g4.w + xp.w);
    size_t off = (size_t)(b0+b)*512 + u;
    float cn = fmaf(gf, cbuf[off], gi*gg);
    cbuf[off] = cn;
    float hn = go * tanhf(cn);
    hbfnext[(size_t)(b0+b)*512 + (u ^ ((b&7)<<3))] = f2bf(hn);
  }
}

// ---------------- final output (t = 199) from bf16 h ----------------
__global__ __launch_bounds__(64) void final_k(const unsigned short* __restrict__ hbf,
    const float* __restrict__ lf0w, const float* __restrict__ lf0b,
    const float* __restrict__ uvw, const float* __restrict__ uvb,
    float* __restrict__ dout){
  int b = blockIdx.x; int lane = threadIdx.x;
  float p0=0.f, p1=0.f;
  for(int k=lane;k<512;k+=64){
    float hv = bf2f(hbf[(size_t)b*512 + (k ^ ((b&7)<<3))]);
    p0 = fmaf(hv, lf0w[k], p0);
    p1 = fmaf(hv, uvw[k], p1);
  }
  for(int off=32; off; off>>=1){
    p0 += __shfl_down(p0, off, 64);
    p1 += __shfl_down(p1, off, 64);
  }
  if(lane==0){
    dout[(size_t)b*(2*NSTEPS) + 199*2 + 0] = p0 + lf0b[0];
    dout[(size_t)b*(2*NSTEPS) + 199*2 + 1] = sigm(p1 + uvb[0]);
  }
}

extern "C" void kernel_launch(void* const* d_in, const int* in_sizes, int n_in,
                              void* d_out, int out_size, void* d_ws, size_t ws_size,
                              hipStream_t stream) {
  const float* x    = (const float*)d_in[0];
  const float* cw0  = (const float*)d_in[2];  const float* cb0 = (const float*)d_in[3];
  const float* cw1  = (const float*)d_in[4];  const float* cb1 = (const float*)d_in[5];
  const float* cw2  = (const float*)d_in[6];  const float* cb2 = (const float*)d_in[7];
  const float* cw3  = (const float*)d_in[8];  const float* cb3 = (const float*)d_in[9];
  const float* cw4  = (const float*)d_in[10]; const float* cb4 = (const float*)d_in[11];
  const float* phw  = (const float*)d_in[12]; const float* phb = (const float*)d_in[13];
  const float* pcw  = (const float*)d_in[14]; const float* pcb = (const float*)d_in[15];
  const float* wih  = (const float*)d_in[16]; const float* whh = (const float*)d_in[17];
  const float* bih  = (const float*)d_in[18]; const float* bhh = (const float*)d_in[19];
  const float* lf0w = (const float*)d_in[20]; const float* lf0b = (const float*)d_in[21];
  const float* uvw  = (const float*)d_in[22]; const float* uvb  = (const float*)d_in[23];
  const float* embw = (const float*)d_in[24]; const float* embb = (const float*)d_in[25];
  float* dout = (float*)d_out;

  float* ws = (float*)d_ws;
  unsigned short* act0 = (unsigned short*)ws;
  unsigned short* act2 = (unsigned short*)ws;
  unsigned short* act4 = (unsigned short*)ws;
  float*          part = ws + 2883584;                      // conv partials
  unsigned short* wproj= (unsigned short*)(ws + 2883584);   // proj weights (after convs)
  unsigned short* hflatb=(unsigned short*)(ws + 7077888);   // 2 MB
  unsigned short* act1 = (unsigned short*)(ws + 8519680);
  unsigned short* act3 = (unsigned short*)(ws + 8519680);
  float*          ppart= ws + 8519680;                      // proj partials (8 MB, region B)
  unsigned short* wpk1 = (unsigned short*)(ws + 12976128);
  unsigned short* wpk2 = wpk1 + 262144;
  unsigned short* wpk3 = wpk2 + 1048576;
  unsigned short* wpk4 = wpk3 + 4194304;
  unsigned short* wpb = (unsigned short*)(ws + 24117248);
  float*  E0  = ws + 24641536;
  float*  E1  = E0 + 2048;
  float*  BX  = E1 + 2048;
  float*  B0  = BX + 2048;
  float*  cb  = ws + 24649728;
  unsigned short* hbf0 = (unsigned short*)(ws + 24715264);
  unsigned short* hbf1 = (unsigned short*)(ws + 24748032);

  // ---- packs & pads ----
  packw_k<<<(128*64*32+255)/256, 256, 0, stream>>>(cw1, wpk1, 128*64*32);
  packw_k<<<(256*128*32+255)/256, 256, 0, stream>>>(cw2, wpk2, 256*128*32);
  packw_k<<<(512*256*32+255)/256, 256, 0, stream>>>(cw3, wpk3, 512*256*32);
  packw_k<<<(1024*512*32+255)/256, 256, 0, stream>>>(cw4, wpk4, 1024*512*32);
  packwlstm_k<<<4096, 256, 0, stream>>>(whh, wpb);
  pack_e2_k<<<512, 256, 0, stream>>>(wih, bih, bhh, embw, embb, E0, E1, BX, B0);
  zpad_k<<<(128*64*8+255)/256, 256, 0, stream>>>(act0, 128*64, 2048);
  zpad_k<<<(128*128*8+255)/256, 256, 0, stream>>>(act1, 128*128, 512);

  // ---- conv stack ----
  conv0_k<<<1024, 256, 0, stream>>>(x, cw0, cb0, act0);
  conv_mfma_k<64,2048,512,128,1,128,1><<<512, 256, 0, stream>>>(act0, wpk1, cb1, act1, nullptr);
  zpad_k<<<(128*256*8+255)/256, 256, 0, stream>>>(act2, 128*256, 128);
  conv_mfma_k<128,512,128,128,1,256,1><<<256, 256, 0, stream>>>(act1, wpk2, cb2, act2, nullptr);
  zpad_k<<<(128*512*8+255)/256, 256, 0, stream>>>(act3, 128*512, 32);
  conv_mfma_k<256,128,32,32,4,512,2><<<256, 256, 0, stream>>>(act2, wpk3, cb3, nullptr, part);
  reduce_k<512,4096,32,2><<<2048, 256, 0, stream>>>(part, cb3, act3);
  conv_mfma_k<512,32,8,8,16,1024,4><<<256, 256, 0, stream>>>(act3, wpk4, cb4, nullptr, part);
  reduce_k<1024,1024,8,4><<<1024, 256, 0, stream>>>(part, cb4, act4);

  // ---- proj (MFMA, K-split) ----
  packwproj_k<<<32768, 256, 0, stream>>>(phw, pcw, wproj);
  gather_k<<<512, 256, 0, stream>>>(act4, hflatb);
  projm2_k<<<128, 256, 0, stream>>>(hflatb, wproj, ppart);
  reduceproj_k<<<128, 256, 0, stream>>>(ppart, phb, pcb, hbf0, cb);

  // ---- LSTM (per-step launches; kernel-launch boundary is the cheap sync) ----
  for(int t=0; t<NSTEPS; t++){
    unsigned short* hp = (t & 1) ? hbf1 : hbf0;
    unsigned short* hn = (t & 1) ? hbf0 : hbf1;
    lstm4_k<<<256, 256, 0, stream>>>(hp, hn, cb, wpb,
        (const float4*)E0, (const float4*)E1, (const float4*)BX, (const float4*)B0,
        lf0w, lf0b, uvw, uvb, dout, t);
  }
  final_k<<<128, 64, 0, stream>>>(hbf0, lf0w, lf0b, uvw, uvb, dout);
}

// Round 10
// 1247.947 us; speedup vs baseline: 7.1938x; 1.0483x over previous
//
#include <hip/hip_runtime.h>

#define NSTEPS 200

typedef __attribute__((ext_vector_type(8))) short bf16x8;
typedef __attribute__((ext_vector_type(4))) float f32x4;

__device__ __forceinline__ float sigm(float x){ return 1.0f/(1.0f + __expf(-x)); }

__device__ __forceinline__ unsigned short f2bf(float f){
  unsigned int u = __float_as_uint(f);
  u = u + 0x7FFFu + ((u>>16)&1u);
  return (unsigned short)(u>>16);
}
__device__ __forceinline__ float bf2f(unsigned short s){
  return __uint_as_float(((unsigned int)s)<<16);
}

__device__ __forceinline__ void gld_lds16(const void* g, void* l){
  __builtin_amdgcn_global_load_lds(
    (const __attribute__((address_space(1))) unsigned int*)g,
    (__attribute__((address_space(3))) unsigned int*)l, 16, 0, 0);
}

// ---------------- fused prep: conv-weight packs + LSTM wq pack + act0/act1 pads ----------------
__global__ __launch_bounds__(256) void prep_k(
    const float* __restrict__ cw1, const float* __restrict__ cw2,
    const float* __restrict__ cw3, const float* __restrict__ cw4,
    unsigned short* __restrict__ wpk1, unsigned short* __restrict__ wpk2,
    unsigned short* __restrict__ wpk3, unsigned short* __restrict__ wpk4,
    const float* __restrict__ whh, uint4* __restrict__ wq,
    unsigned short* __restrict__ act0, unsigned short* __restrict__ act1)
{
  const int N1=262144, N2=1048576, N3=4194304, N4=16777216, NQ=131072, NZ0=65536, NZ1=131072;
  int i = blockIdx.x*256 + threadIdx.x;
  if(i < N1){
    int k = i & 31; int r = i >> 5;
    wpk1[i] = (k >= 1) ? f2bf(cw1[(size_t)r*31 + (k-1)]) : (unsigned short)0;
    return;
  }
  i -= N1;
  if(i < N2){
    int k = i & 31; int r = i >> 5;
    wpk2[i] = (k >= 1) ? f2bf(cw2[(size_t)r*31 + (k-1)]) : (unsigned short)0;
    return;
  }
  i -= N2;
  if(i < N3){
    int k = i & 31; int r = i >> 5;
    wpk3[i] = (k >= 1) ? f2bf(cw3[(size_t)r*31 + (k-1)]) : (unsigned short)0;
    return;
  }
  i -= N3;
  if(i < N4){
    int k = i & 31; int r = i >> 5;
    wpk4[i] = (k >= 1) ? f2bf(cw4[(size_t)r*31 + (k-1)]) : (unsigned short)0;
    return;
  }
  i -= N4;
  if(i < NQ){
    // wq frag f: [ut][wn][ks][lane=kg*16+l15], 16B each
    int l15 = i&15, kg = (i>>4)&3, ks = (i>>6)&15, wn = (i>>10)&3, ut = i>>12;
    int n = ut*64 + wn*16 + l15;
    int u = n >> 2, g = n & 3;
    int k0 = ks*32 + kg*8;
    const float* src = whh + (size_t)(g*512+u)*512 + k0;
    unsigned short o[8];
    #pragma unroll
    for(int e=0;e<8;e++) o[e] = f2bf(src[e]);
    wq[i] = *(uint4*)o;
    return;
  }
  i -= NQ;
  if(i < NZ0){
    int row = i>>3; int j = i&7;
    int off = (j<4) ? j*4 : (16 + 2048 + (j-4)*4);
    ushort4 z; z.x=0; z.y=0; z.z=0; z.w=0;
    *(ushort4*)&act0[(size_t)row*2080 + off] = z;
    return;
  }
  i -= NZ0;
  if(i < NZ1){
    int row = i>>3; int j = i&7;
    int off = (j<4) ? j*4 : (16 + 512 + (j-4)*4);
    ushort4 z; z.x=0; z.y=0; z.z=0; z.w=0;
    *(ushort4*)&act1[(size_t)row*544 + off] = z;
  }
}

// ---------------- zero row pads of a padded bf16 activation buffer (mid-stream) ----------------
__global__ __launch_bounds__(256) void zpad_k(unsigned short* __restrict__ p, int nrows, int L){
  int idx = blockIdx.x*256 + threadIdx.x;
  if(idx >= nrows*8) return;
  int row = idx>>3; int j = idx&7;
  int off = (j<4) ? j*4 : (16 + L + (j-4)*4);
  ushort4 z; z.x=0; z.y=0; z.z=0; z.w=0;
  *(ushort4*)&p[(size_t)row*(L+32) + off] = z;
}

// ---------------- conv0: Cin=1, Cout=64, L 8192->2048, fp32 VALU, bf16 padded out ----------------
__global__ __launch_bounds__(256) void conv0_k(const float* __restrict__ x,
    const float* __restrict__ w, const float* __restrict__ bias, unsigned short* __restrict__ act0){
  __shared__ float xl[1056];
  __shared__ float wl[64*31];
  __shared__ float bl[64];
  int b = blockIdx.x >> 3; int lt = blockIdx.x & 7;
  int l0 = lt*256; int tid = threadIdx.x;
  for(int i=tid;i<1056;i+=256){
    int g = 4*l0 - 15 + i;
    xl[i] = (g>=0 && g<8192) ? x[(size_t)b*8192 + g] : 0.f;
  }
  for(int i=tid;i<1984;i+=256) wl[i] = w[i];
  if(tid<64) bl[tid]=bias[tid];
  __syncthreads();
  float xr[31];
  #pragma unroll
  for(int j=0;j<31;j++) xr[j] = xl[4*tid + j];
  size_t obase = ((size_t)b*64)*2080 + 16 + l0 + tid;
  for(int co=0;co<64;co++){
    float acc = bl[co];
    #pragma unroll
    for(int j=0;j<31;j++) acc = fmaf(wl[co*31+j], xr[j], acc);
    act0[obase + (size_t)co*2080] = f2bf(fmaxf(acc,0.f));
  }
}

// ---------------- generic MFMA conv (as GEMM M=(b,l), N=co, K=ci*32+tap) ----------------
template<int CIN, int LIN, int LOUT, int LT, int NBT, int COUT, int KSPLIT>
__global__ __launch_bounds__(256,3) void conv_mfma_k(
    const unsigned short* __restrict__ actin,
    const unsigned short* __restrict__ wpk,
    const float* __restrict__ bias,
    unsigned short* __restrict__ actout,
    float* __restrict__ partial)
{
  constexpr int LINP  = LIN + 32;
  constexpr int LOUTP = LOUT + 32;
  constexpr int SPANB = 8*LT + 64;
  constexpr int SC    = SPANB/16;
  constexpr int CA    = 2*NBT*SC;
  static_assert(CA <= 256, "CA");
  constexpr int ASZ   = CA*16;
  constexpr int BSZ   = 16384;
  constexpr int MT    = 128*LOUT;
  constexpr int MTILES= MT/128;
  constexpr int NT    = COUT/128;
  constexpr int NSTEP = CIN/2/KSPLIT;
  constexpr int GRID  = MTILES*NT*KSPLIT;
  static_assert(GRID % 8 == 0, "grid%8");
  __shared__ __align__(16) char smem[2*(BSZ+ASZ)];
  char* Bb = smem;
  char* Ab = smem + 2*BSZ;

  // XCD-aware swizzle: consecutive LOGICAL bids (sharing the (nt,z) weight
  // slice) land on ONE XCD.
  int bid = (blockIdx.x & 7)*(GRID/8) + (blockIdx.x >> 3);
  int mt = bid % MTILES; bid /= MTILES;
  int nt = bid % NT;     int z = bid / NT;
  int b0 = (mt*128)/LOUT;
  int l0 = (mt*128)%LOUT;
  int cobase = nt*128;
  int s0 = z*NSTEP, s1 = s0 + NSTEP;

  int tid = threadIdx.x; int lane = tid&63; int wid = tid>>6;
  int wm = wid>>1, wn = wid&1;
  int l15 = lane&15, kg = lane>>4;

  int aq_c=0, aq_b=0, aq_j=0; bool a_act = tid < CA;
  { int q = tid; aq_c = q/(NBT*SC); int r = q%(NBT*SC); aq_b = r/SC; aq_j = r%SC; }

  auto STAGE = [&](int st){
    int buf = st&1;
    #pragma unroll
    for(int i=0;i<4;i++){
      int qb = tid + i*256;
      int col = qb>>3; int j = qb&7;
      const char* src = (const char*)wpk + (size_t)(cobase+col)*(CIN*64) + (size_t)st*128
                        + ((j*16) ^ ((col&7)<<4));
      gld_lds16(src, Bb + buf*BSZ + qb*16);
    }
    if(a_act){
      int ci = 2*st + aq_c;
      const char* src = (const char*)actin
          + 2*((size_t)((b0+aq_b)*CIN + ci)*LINP + 4*l0) + aq_j*16;
      gld_lds16(src, Ab + buf*ASZ + tid*16);
    }
  };

  int abyte[2][4], bbyte[2][4];
  #pragma unroll
  for(int c=0;c<2;c++){
    #pragma unroll
    for(int mf=0;mf<4;mf++){
      int r = wm*64 + mf*16 + l15;
      int bp = (NBT>1) ? (r/LT) : 0;
      int ll = (NBT>1) ? (r%LT) : r;
      abyte[c][mf] = (c*NBT + bp)*SPANB + 8*ll + 16*kg;
    }
    #pragma unroll
    for(int nf=0;nf<4;nf++){
      int col = wn*64 + nf*16 + l15;
      bbyte[c][nf] = col*128 + ((c*64 + 16*kg) ^ ((col&7)<<4));
    }
  }

  const f32x4 vz = {0.f,0.f,0.f,0.f};
  f32x4 acc[4][4];
  #pragma unroll
  for(int i=0;i<4;i++)
    #pragma unroll
    for(int j=0;j<4;j++) acc[i][j] = vz;

  STAGE(s0);
  __syncthreads();
  for(int s=s0;s<s1;s++){
    if(s+1<s1) STAGE(s+1);
    const char* Ac = Ab + (s&1)*ASZ;
    const char* Bc = Bb + (s&1)*BSZ;
    #pragma unroll
    for(int c=0;c<2;c++){
      bf16x8 af[4], bfv[4];
      #pragma unroll
      for(int mf=0;mf<4;mf++){
        const char* ap = Ac + abyte[c][mf];
        union { unsigned long long u[2]; bf16x8 v; } t;
        t.u[0] = *(const unsigned long long*)ap;
        t.u[1] = *(const unsigned long long*)(ap+8);
        af[mf] = t.v;
      }
      #pragma unroll
      for(int nf=0;nf<4;nf++) bfv[nf] = *(const bf16x8*)(Bc + bbyte[c][nf]);
      #pragma unroll
      for(int mf=0;mf<4;mf++)
        #pragma unroll
        for(int nf=0;nf<4;nf++)
          acc[mf][nf] = __builtin_amdgcn_mfma_f32_16x16x32_bf16(af[mf], bfv[nf], acc[mf][nf], 0,0,0);
    }
    __syncthreads();
  }

  if constexpr (KSPLIT == 1){
    #pragma unroll
    for(int nf=0;nf<4;nf++){
      int co = cobase + wn*64 + nf*16 + l15;
      float bv = bias[co];
      #pragma unroll
      for(int mf=0;mf<4;mf++){
        int m = wm*64 + mf*16 + 4*kg;
        int bp = (NBT>1) ? (m/LT) : 0;
        int ll = (NBT>1) ? (m%LT) : m;
        f32x4 a = acc[mf][nf];
        ushort4 o;
        o.x = f2bf(fmaxf(a[0]+bv,0.f));
        o.y = f2bf(fmaxf(a[1]+bv,0.f));
        o.z = f2bf(fmaxf(a[2]+bv,0.f));
        o.w = f2bf(fmaxf(a[3]+bv,0.f));
        size_t off = ((size_t)((b0+bp)*COUT + co))*LOUTP + 16 + l0 + ll;
        *(ushort4*)&actout[off] = o;
      }
    }
  } else {
    #pragma unroll
    for(int nf=0;nf<4;nf++){
      int co = cobase + wn*64 + nf*16 + l15;
      #pragma unroll
      for(int mf=0;mf<4;mf++){
        int mloc = wm*64 + mf*16 + 4*kg;
        int mglob = mt*128 + mloc;
        *(f32x4*)&partial[((size_t)(z*COUT + co))*MT + mglob] = acc[mf][nf];
      }
    }
  }
}

// ---------------- reduce K-split partials -> bf16 padded act ----------------
template<int COUT, int MT, int LOUT, int KS>
__global__ __launch_bounds__(256) void reduce_k(const float* __restrict__ partial,
    const float* __restrict__ bias, unsigned short* __restrict__ actout){
  int idx = blockIdx.x*256 + threadIdx.x;
  if(idx >= COUT*(MT/4)) return;
  int m4 = idx % (MT/4); int co = idx / (MT/4);
  int m = m4*4;
  float4 a = *(const float4*)&partial[(size_t)co*MT + m];
  #pragma unroll
  for(int zz=1; zz<KS; zz++){
    float4 b = *(const float4*)&partial[((size_t)(zz*COUT + co))*MT + m];
    a.x += b.x; a.y += b.y; a.z += b.z; a.w += b.w;
  }
  float bv = bias[co];
  int b_ = m / LOUT, l = m % LOUT;
  ushort4 o;
  o.x = f2bf(fmaxf(a.x+bv,0.f));
  o.y = f2bf(fmaxf(a.y+bv,0.f));
  o.z = f2bf(fmaxf(a.z+bv,0.f));
  o.w = f2bf(fmaxf(a.w+bv,0.f));
  *(ushort4*)&actout[((size_t)(b_*COUT + co))*(LOUT+32) + 16 + l] = o;
}

// ---------------- gather act4 -> hflatb bf16 [B][8192], pre-swizzled by batch ----------------
__global__ __launch_bounds__(256) void gather_k(const unsigned short* __restrict__ act4,
    unsigned short* __restrict__ hflatb){
  __shared__ unsigned short trans[8][260];
  int b = blockIdx.x >> 2, ct = blockIdx.x & 3;
  int c0 = ct*256;
  int tid = threadIdx.x;
  uint4 v = *(const uint4*)&act4[((size_t)(b*1024 + c0 + tid))*40 + 16];
  unsigned short* pv = (unsigned short*)&v;
  #pragma unroll
  for(int l=0;l<8;l++) trans[l][tid] = pv[l];
  __syncthreads();
  int l = tid>>5, cg_ = tid&31;
  uint4 o;
  unsigned short* po = (unsigned short*)&o;
  #pragma unroll
  for(int e=0;e<8;e++) po[e] = trans[l][cg_*8+e];
  int G = l*128 + ct*32 + cg_;
  *(uint4*)&hflatb[(size_t)b*8192 + (size_t)((G ^ (b&7))*8)] = o;
}

// ---------------- pack proj weights: [1024 n][8192 d] bf16 ----------------
__global__ __launch_bounds__(256) void packwproj_k(const float* __restrict__ phw,
    const float* __restrict__ pcw, unsigned short* __restrict__ wproj){
  int idx = blockIdx.x*256 + threadIdx.x;
  if(idx >= 1024*8192) return;
  int n = idx >> 13, d = idx & 8191;
  float v = (n < 512) ? phw[(size_t)n*8192 + d] : pcw[(size_t)(n-512)*8192 + d];
  wproj[idx] = f2bf(v);
}

// ---------------- pack E vectors (wave-parallel) ----------------
__global__ __launch_bounds__(256) void pack_e2_k(const float* __restrict__ wih,
    const float* __restrict__ bih, const float* __restrict__ bhh,
    const float* __restrict__ embw, const float* __restrict__ embb,
    float* __restrict__ E0, float* __restrict__ E1, float* __restrict__ BX, float* __restrict__ B0){
  int row = blockIdx.x*4 + (threadIdx.x>>6);
  int lane = threadIdx.x & 63;
  const float* wr = wih + (size_t)row*512;
  float e0=0.f, e1=0.f, bx=0.f;
  #pragma unroll
  for(int e=0;e<8;e++){
    int j = lane + 64*e;
    float wv = wr[j];
    e0 = fmaf(wv, embw[j*2+0], e0);
    e1 = fmaf(wv, embw[j*2+1], e1);
    bx = fmaf(wv, embb[j], bx);
  }
  #pragma unroll
  for(int off=32; off; off>>=1){
    e0 += __shfl_down(e0, off, 64);
    e1 += __shfl_down(e1, off, 64);
    bx += __shfl_down(bx, off, 64);
  }
  if(lane==0){
    int u = row & 511, g = row >> 9;
    float b0v = bih[row] + bhh[row];
    E0[u*4+g] = e0; E1[u*4+g] = e1; BX[u*4+g] = bx + b0v; B0[u*4+g] = b0v;
  }
}

// ---------------- projection via MFMA, K-split: grid 128 = 8 nt x 16 zk ----------------
__global__ __launch_bounds__(256,2) void projm2_k(
    const unsigned short* __restrict__ hflatb,
    const unsigned short* __restrict__ wproj,
    float* __restrict__ partial)      // [16 zk][1024 n][128 b]
{
  __shared__ __align__(16) char smem[2*(16384+16384)];
  char* Bb = smem;
  char* Ab = smem + 32768;
  int bid = blockIdx.x;
  int zk = bid & 15, nt = bid >> 4;
  int n0 = nt*128;
  int tid = threadIdx.x, lane = tid&63, wid = tid>>6;
  int wm = wid>>1, wn = wid&1;
  int l15 = lane&15, kg = lane>>4;

  auto STAGE = [&](int kc){
    int buf = kc&1;
    #pragma unroll
    for(int i=0;i<4;i++){
      int q = tid + i*256;
      int col = q>>3, j = q&7;
      const char* src = (const char*)wproj + (size_t)(n0+col)*16384
                        + (size_t)zk*1024 + kc*128 + ((j*16) ^ ((col&7)<<4));
      gld_lds16(src, Bb + buf*16384 + q*16);
    }
    #pragma unroll
    for(int i=0;i<4;i++){
      int q = tid + i*256;
      int row = q>>3, j = q&7;
      // hflatb is ALREADY pre-swizzled in global (gather_k) -> stage LINEARLY.
      const char* src = (const char*)hflatb + (size_t)row*16384
                        + (size_t)zk*1024 + kc*128 + j*16;
      gld_lds16(src, Ab + buf*16384 + q*16);
    }
  };

  const f32x4 vz = {0.f,0.f,0.f,0.f};
  f32x4 acc[4][4];
  #pragma unroll
  for(int i=0;i<4;i++)
    #pragma unroll
    for(int j=0;j<4;j++) acc[i][j] = vz;

  STAGE(0);
  __syncthreads();
  for(int kc=0;kc<8;kc++){
    if(kc<7) STAGE(kc+1);
    const char* Ac = Ab + (kc&1)*16384;
    const char* Bc = Bb + (kc&1)*16384;
    #pragma unroll
    for(int c=0;c<2;c++){
      bf16x8 af[4], bfv[4];
      #pragma unroll
      for(int mf=0;mf<4;mf++){
        int row = wm*64 + mf*16 + l15;
        af[mf] = *(const bf16x8*)(Ac + row*128 + ((c*64 + kg*16) ^ ((row&7)<<4)));
      }
      #pragma unroll
      for(int nf=0;nf<4;nf++){
        int col = wn*64 + nf*16 + l15;
        bfv[nf] = *(const bf16x8*)(Bc + col*128 + ((c*64 + kg*16) ^ ((col&7)<<4)));
      }
      #pragma unroll
      for(int mf=0;mf<4;mf++)
        #pragma unroll
        for(int nf=0;nf<4;nf++)
          acc[mf][nf] = __builtin_amdgcn_mfma_f32_16x16x32_bf16(af[mf], bfv[nf], acc[mf][nf], 0,0,0);
    }
    __syncthreads();
  }
  #pragma unroll
  for(int nf=0;nf<4;nf++){
    int n = n0 + wn*64 + nf*16 + l15;
    #pragma unroll
    for(int mf=0;mf<4;mf++){
      int m = wm*64 + mf*16 + kg*4;
      *(f32x4*)&partial[((size_t)zk*1024 + n)*128 + m] = acc[mf][nf];
    }
  }
}

// ---------------- reduce proj partials -> hbf0 (swizzled bf16) + cbuf ----------------
__global__ __launch_bounds__(256) void reduceproj_k(const float* __restrict__ partial,
    const float* __restrict__ phb, const float* __restrict__ pcb,
    unsigned short* __restrict__ hbf0, float* __restrict__ cbuf){
  int idx = blockIdx.x*256 + threadIdx.x;    // 32768 = 1024 n x 32 b-quads
  int n = idx >> 5; int b4 = (idx & 31)*4;
  const float* p = partial + (size_t)n*128 + b4;
  float4 a = *(const float4*)p;
  #pragma unroll
  for(int z=1; z<16; z++){
    float4 v = *(const float4*)(p + (size_t)z*131072);
    a.x+=v.x; a.y+=v.y; a.z+=v.z; a.w+=v.w;
  }
  float av[4] = {a.x, a.y, a.z, a.w};
  if(n < 512){
    float bv = phb[n];
    #pragma unroll
    for(int j=0;j<4;j++){
      int b = b4 + j;
      hbf0[(size_t)b*512 + (n ^ ((b&7)<<3))] = f2bf(av[j] + bv);
    }
  } else {
    float bv = pcb[n-512];
    #pragma unroll
    for(int j=0;j<4;j++){
      int b = b4 + j;
      cbuf[(size_t)b*512 + (n-512)] = av[j] + bv;
    }
  }
}

// ---------------- LSTM step v5: W direct-to-register (coalesced wq), A in LDS ----------------
__global__ __launch_bounds__(256) void lstm5_k(
    const unsigned short* __restrict__ hbfprev,
    unsigned short* __restrict__ hbfnext,
    float* __restrict__ cbuf,
    const uint4* __restrict__ wq,
    const float4* __restrict__ E0v, const float4* __restrict__ E1v,
    const float4* __restrict__ BXv, const float4* __restrict__ B0v,
    const float* __restrict__ lf0w, const float* __restrict__ lf0b,
    const float* __restrict__ uvw, const float* __restrict__ uvb,
    float* __restrict__ dout, int t)
{
  __shared__ __align__(16) char A[16384];        // 16 rows x 1024 B (XOR-swizzled)
  __shared__ __align__(16) float gates[16][68];
  __shared__ float red0[16][17], red1[16][17];
  __shared__ float lf_s[16], uv_s[16];

  int bid = blockIdx.x;
  int ut = bid & 31, bt = bid >> 5;
  int b0 = bt*16;
  int tid = threadIdx.x, lane = tid&63, wn = tid>>6;
  int l15 = lane&15, kg = lane>>4;

  // stage h (16 KB) into LDS; W frags direct to registers (coalesced 1KB/wave/instr)
  #pragma unroll
  for(int i=0;i<4;i++){
    int q = i*256 + tid;
    gld_lds16((const char*)hbfprev + (size_t)b0*1024 + q*16, A + q*16);
  }
  const uint4* wbase = wq + ((size_t)(ut*4+wn)*16)*64 + lane;
  bf16x8 w[16];
  #pragma unroll
  for(int ks=0;ks<16;ks++){
    uint4 v = wbase[(size_t)ks*64];
    w[ks] = *(bf16x8*)&v;
  }
  asm volatile("s_waitcnt vmcnt(0)");
  __syncthreads();

  // gates GEMM: one 16-col tile per wave, K=512 in 16 MFMAs, B from registers
  const f32x4 vz = {0.f,0.f,0.f,0.f};
  f32x4 acc = vz;
  int c = wn*16 + l15;
  int aswz = (l15&7)<<4;
  #pragma unroll
  for(int ks=0; ks<16; ks++){
    bf16x8 af = *(const bf16x8*)(A + l15*1024 + ((ks*64 + kg*16) ^ aswz));
    acc = __builtin_amdgcn_mfma_f32_16x16x32_bf16(af, w[ks], acc, 0,0,0);
  }
  #pragma unroll
  for(int j=0;j<4;j++) gates[kg*4+j][c] = acc[j];

  // heads for output t-1 (from staged h_prev)
  int hb = tid & 15, hs = tid >> 4;
  if(t > 0){
    float p0 = 0.f, p1 = 0.f;
    #pragma unroll
    for(int j=0;j<4;j++){
      bf16x8 hv = *(const bf16x8*)(A + hb*1024 + ((hs*64 + j*16) ^ ((hb&7)<<4)));
      #pragma unroll
      for(int e=0;e<8;e++){
        float h = bf2f((unsigned short)hv[e]);
        int k = hs*32 + j*8 + e;
        p0 = fmaf(h, lf0w[k], p0);
        p1 = fmaf(h, uvw[k], p1);
      }
    }
    red0[hs][hb] = p0; red1[hs][hb] = p1;
  }
  __syncthreads();
  if(t > 0 && tid < 16){
    float a0=0.f, a1=0.f;
    #pragma unroll
    for(int s2=0;s2<16;s2++){ a0 += red0[s2][tid]; a1 += red1[s2][tid]; }
    a0 += lf0b[0];
    a1 = sigm(a1 + uvb[0]);
    lf_s[tid] = a0; uv_s[tid] = a1;
    if(ut == 0){
      dout[(size_t)(b0+tid)*(2*NSTEPS) + (t-1)*2 + 0] = a0;
      dout[(size_t)(b0+tid)*(2*NSTEPS) + (t-1)*2 + 1] = a1;
    }
  }
  __syncthreads();

  // epilogue: one (b, u) per thread: 16 b x 16 u
  {
    int b = tid & 15, ul = tid >> 4;
    int u = ut*16 + ul;
    float4 g4 = *(const float4*)&gates[b][ul*4];
    float4 xp;
    if(t == 0){
      xp = B0v[u];
    } else {
      float lf = lf_s[b], uvv = uv_s[b];
      float4 e0 = E0v[u], e1 = E1v[u], bx = BXv[u];
      xp.x = fmaf(lf, e0.x, fmaf(uvv, e1.x, bx.x));
      xp.y = fmaf(lf, e0.y, fmaf(uvv, e1.y, bx.y));
      xp.z = fmaf(lf, e0.z, fmaf(uvv, e1.z, bx.z));
      xp.w = fmaf(lf, e0.w, fmaf(uvv, e1.w, bx.w));
    }
    float gi = sigm(g4.x + xp.x);
    float gf = sigm(g4.y + xp.y);
    float gg = tanhf(g4.z + xp.z);
    float go = sigm(g4.w + xp.w);
    size_t off = (size_t)(b0+b)*512 + u;
    float cn = fmaf(gf, cbuf[off], gi*gg);
    cbuf[off] = cn;
    float hn = go * tanhf(cn);
    hbfnext[(size_t)(b0+b)*512 + (u ^ ((b&7)<<3))] = f2bf(hn);
  }
}

// ---------------- final output (t = 199) from bf16 h ----------------
__global__ __launch_bounds__(64) void final_k(const unsigned short* __restrict__ hbf,
    const float* __restrict__ lf0w, const float* __restrict__ lf0b,
    const float* __restrict__ uvw, const float* __restrict__ uvb,
    float* __restrict__ dout){
  int b = blockIdx.x; int lane = threadIdx.x;
  float p0=0.f, p1=0.f;
  for(int k=lane;k<512;k+=64){
    float hv = bf2f(hbf[(size_t)b*512 + (k ^ ((b&7)<<3))]);
    p0 = fmaf(hv, lf0w[k], p0);
    p1 = fmaf(hv, uvw[k], p1);
  }
  for(int off=32; off; off>>=1){
    p0 += __shfl_down(p0, off, 64);
    p1 += __shfl_down(p1, off, 64);
  }
  if(lane==0){
    dout[(size_t)b*(2*NSTEPS) + 199*2 + 0] = p0 + lf0b[0];
    dout[(size_t)b*(2*NSTEPS) + 199*2 + 1] = sigm(p1 + uvb[0]);
  }
}

extern "C" void kernel_launch(void* const* d_in, const int* in_sizes, int n_in,
                              void* d_out, int out_size, void* d_ws, size_t ws_size,
                              hipStream_t stream) {
  const float* x    = (const float*)d_in[0];
  const float* cw0  = (const float*)d_in[2];  const float* cb0 = (const float*)d_in[3];
  const float* cw1  = (const float*)d_in[4];  const float* cb1 = (const float*)d_in[5];
  const float* cw2  = (const float*)d_in[6];  const float* cb2 = (const float*)d_in[7];
  const float* cw3  = (const float*)d_in[8];  const float* cb3 = (const float*)d_in[9];
  const float* cw4  = (const float*)d_in[10]; const float* cb4 = (const float*)d_in[11];
  const float* phw  = (const float*)d_in[12]; const float* phb = (const float*)d_in[13];
  const float* pcw  = (const float*)d_in[14]; const float* pcb = (const float*)d_in[15];
  const float* wih  = (const float*)d_in[16]; const float* whh = (const float*)d_in[17];
  const float* bih  = (const float*)d_in[18]; const float* bhh = (const float*)d_in[19];
  const float* lf0w = (const float*)d_in[20]; const float* lf0b = (const float*)d_in[21];
  const float* uvw  = (const float*)d_in[22]; const float* uvb  = (const float*)d_in[23];
  const float* embw = (const float*)d_in[24]; const float* embb = (const float*)d_in[25];
  float* dout = (float*)d_out;

  float* ws = (float*)d_ws;
  unsigned short* act0 = (unsigned short*)ws;
  unsigned short* act2 = (unsigned short*)ws;
  unsigned short* act4 = (unsigned short*)ws;
  float*          part = ws + 2883584;                      // conv partials
  unsigned short* wproj= (unsigned short*)(ws + 2883584);   // proj weights (after convs)
  unsigned short* hflatb=(unsigned short*)(ws + 7077888);   // 2 MB
  unsigned short* act1 = (unsigned short*)(ws + 8519680);
  unsigned short* act3 = (unsigned short*)(ws + 8519680);
  float*          ppart= ws + 8519680;                      // proj partials (8 MB, region B)
  unsigned short* wpk1 = (unsigned short*)(ws + 12976128);
  unsigned short* wpk2 = wpk1 + 262144;
  unsigned short* wpk3 = wpk2 + 1048576;
  unsigned short* wpk4 = wpk3 + 4194304;
  uint4*          wq   = (uint4*)(ws + 24117248);           // 2 MB (131072 x 16B)
  float*  E0  = ws + 24641536;
  float*  E1  = E0 + 2048;
  float*  BX  = E1 + 2048;
  float*  B0  = BX + 2048;
  float*  cb  = ws + 24649728;
  unsigned short* hbf0 = (unsigned short*)(ws + 24715264);
  unsigned short* hbf1 = (unsigned short*)(ws + 24748032);

  // ---- fused prep (packs + pads) ----
  prep_k<<<(22609920+255)/256, 256, 0, stream>>>(cw1, cw2, cw3, cw4,
      wpk1, wpk2, wpk3, wpk4, whh, wq, act0, act1);
  pack_e2_k<<<512, 256, 0, stream>>>(wih, bih, bhh, embw, embb, E0, E1, BX, B0);

  // ---- conv stack ----
  conv0_k<<<1024, 256, 0, stream>>>(x, cw0, cb0, act0);
  conv_mfma_k<64,2048,512,128,1,128,1><<<512, 256, 0, stream>>>(act0, wpk1, cb1, act1, nullptr);
  zpad_k<<<(128*256*8+255)/256, 256, 0, stream>>>(act2, 128*256, 128);
  conv_mfma_k<128,512,128,128,1,256,1><<<256, 256, 0, stream>>>(act1, wpk2, cb2, act2, nullptr);
  zpad_k<<<(128*512*8+255)/256, 256, 0, stream>>>(act3, 128*512, 32);
  conv_mfma_k<256,128,32,32,4,512,2><<<256, 256, 0, stream>>>(act2, wpk3, cb3, nullptr, part);
  reduce_k<512,4096,32,2><<<2048, 256, 0, stream>>>(part, cb3, act3);
  conv_mfma_k<512,32,8,8,16,1024,4><<<256, 256, 0, stream>>>(act3, wpk4, cb4, nullptr, part);
  reduce_k<1024,1024,8,4><<<1024, 256, 0, stream>>>(part, cb4, act4);

  // ---- proj (MFMA, K-split) ----
  packwproj_k<<<32768, 256, 0, stream>>>(phw, pcw, wproj);
  gather_k<<<512, 256, 0, stream>>>(act4, hflatb);
  projm2_k<<<128, 256, 0, stream>>>(hflatb, wproj, ppart);
  reduceproj_k<<<128, 256, 0, stream>>>(ppart, phb, pcb, hbf0, cb);

  // ---- LSTM (per-step launches; kernel-launch boundary is the cheap sync) ----
  for(int t=0; t<NSTEPS; t++){
    unsigned short* hp = (t & 1) ? hbf1 : hbf0;
    unsigned short* hn = (t & 1) ? hbf0 : hbf1;
    lstm5_k<<<256, 256, 0, stream>>>(hp, hn, cb, wq,
        (const float4*)E0, (const float4*)E1, (const float4*)BX, (const float4*)B0,
        lf0w, lf0b, uvw, uvb, dout, t);
  }
  final_k<<<128, 64, 0, stream>>>(hbf0, lf0w, lf0b, uvw, uvb, dout);
}

// Round 11
// 1238.239 us; speedup vs baseline: 7.2502x; 1.0078x over previous
//
#include <hip/hip_runtime.h>

#define NSTEPS 200

typedef __attribute__((ext_vector_type(8))) short bf16x8;
typedef __attribute__((ext_vector_type(4))) float f32x4;

__device__ __forceinline__ float sigm(float x){ return 1.0f/(1.0f + __expf(-x)); }

__device__ __forceinline__ unsigned short f2bf(float f){
  unsigned int u = __float_as_uint(f);
  u = u + 0x7FFFu + ((u>>16)&1u);
  return (unsigned short)(u>>16);
}
__device__ __forceinline__ float bf2f(unsigned short s){
  return __uint_as_float(((unsigned int)s)<<16);
}

__device__ __forceinline__ void gld_lds16(const void* g, void* l){
  __builtin_amdgcn_global_load_lds(
    (const __attribute__((address_space(1))) unsigned int*)g,
    (__attribute__((address_space(3))) unsigned int*)l, 16, 0, 0);
}

// ---------------- fused prep v2 (vectorized): conv packs (x4) + wq + pads ----------------
__global__ __launch_bounds__(256) void prep2_k(
    const float* __restrict__ cw1, const float* __restrict__ cw2,
    const float* __restrict__ cw3, const float* __restrict__ cw4,
    unsigned short* __restrict__ wpk1, unsigned short* __restrict__ wpk2,
    unsigned short* __restrict__ wpk3, unsigned short* __restrict__ wpk4,
    const float* __restrict__ whh, uint4* __restrict__ wq,
    unsigned short* __restrict__ act0, unsigned short* __restrict__ act1)
{
  const int Q1=65536, Q2=262144, Q3=1048576, Q4=4194304;   // quarter counts
  const int NQ=131072, NZ0=65536, NZ1=131072;
  int i = blockIdx.x*256 + threadIdx.x;
  if(i < Q1+Q2+Q3+Q4){
    const float* cw; unsigned short* wpk;
    if(i < Q1){ cw=cw1; wpk=wpk1; }
    else if(i < Q1+Q2){ i-=Q1; cw=cw2; wpk=wpk2; }
    else if(i < Q1+Q2+Q3){ i-=Q1+Q2; cw=cw3; wpk=wpk3; }
    else { i-=Q1+Q2+Q3; cw=cw4; wpk=wpk4; }
    int idx4 = i*4;
    int k4 = idx4 & 31; int r = idx4 >> 5;
    ushort4 o;
    unsigned short* po = (unsigned short*)&o;
    #pragma unroll
    for(int e=0;e<4;e++){
      int k = k4 + e;
      po[e] = (k >= 1) ? f2bf(cw[(size_t)r*31 + (k-1)]) : (unsigned short)0;
    }
    *(ushort4*)&wpk[idx4] = o;
    return;
  }
  i -= Q1+Q2+Q3+Q4;
  if(i < NQ){
    // wq frag: [ut][wn][ks][lane=kg*16+l15], 16B each
    int l15 = i&15, kg = (i>>4)&3, ks = (i>>6)&15, wn = (i>>10)&3, ut = i>>12;
    int n = ut*64 + wn*16 + l15;
    int u = n >> 2, g = n & 3;
    int k0 = ks*32 + kg*8;
    const float* src = whh + (size_t)(g*512+u)*512 + k0;
    unsigned short o[8];
    #pragma unroll
    for(int e=0;e<8;e++) o[e] = f2bf(src[e]);
    wq[i] = *(uint4*)o;
    return;
  }
  i -= NQ;
  if(i < NZ0){
    int row = i>>3; int j = i&7;
    int off = (j<4) ? j*4 : (16 + 2048 + (j-4)*4);
    ushort4 z; z.x=0; z.y=0; z.z=0; z.w=0;
    *(ushort4*)&act0[(size_t)row*2080 + off] = z;
    return;
  }
  i -= NZ0;
  if(i < NZ1){
    int row = i>>3; int j = i&7;
    int off = (j<4) ? j*4 : (16 + 512 + (j-4)*4);
    ushort4 z; z.x=0; z.y=0; z.z=0; z.w=0;
    *(ushort4*)&act1[(size_t)row*544 + off] = z;
  }
}

// ---------------- zero row pads (mid-stream) ----------------
__global__ __launch_bounds__(256) void zpad_k(unsigned short* __restrict__ p, int nrows, int L){
  int idx = blockIdx.x*256 + threadIdx.x;
  if(idx >= nrows*8) return;
  int row = idx>>3; int j = idx&7;
  int off = (j<4) ? j*4 : (16 + L + (j-4)*4);
  ushort4 z; z.x=0; z.y=0; z.z=0; z.w=0;
  *(ushort4*)&p[(size_t)row*(L+32) + off] = z;
}

// ---------------- conv0: Cin=1, Cout=64, L 8192->2048, fp32 VALU, bf16 padded out ----------------
__global__ __launch_bounds__(256) void conv0_k(const float* __restrict__ x,
    const float* __restrict__ w, const float* __restrict__ bias, unsigned short* __restrict__ act0){
  __shared__ float xl[1056];
  __shared__ float wl[64*31];
  __shared__ float bl[64];
  int b = blockIdx.x >> 3; int lt = blockIdx.x & 7;
  int l0 = lt*256; int tid = threadIdx.x;
  for(int i=tid;i<1056;i+=256){
    int g = 4*l0 - 15 + i;
    xl[i] = (g>=0 && g<8192) ? x[(size_t)b*8192 + g] : 0.f;
  }
  for(int i=tid;i<1984;i+=256) wl[i] = w[i];
  if(tid<64) bl[tid]=bias[tid];
  __syncthreads();
  float xr[31];
  #pragma unroll
  for(int j=0;j<31;j++) xr[j] = xl[4*tid + j];
  size_t obase = ((size_t)b*64)*2080 + 16 + l0 + tid;
  for(int co=0;co<64;co++){
    float acc = bl[co];
    #pragma unroll
    for(int j=0;j<31;j++) acc = fmaf(wl[co*31+j], xr[j], acc);
    act0[obase + (size_t)co*2080] = f2bf(fmaxf(acc,0.f));
  }
}

// ---------------- generic MFMA conv (as GEMM M=(b,l), N=co, K=ci*32+tap) ----------------
template<int CIN, int LIN, int LOUT, int LT, int NBT, int COUT, int KSPLIT>
__global__ __launch_bounds__(256,3) void conv_mfma_k(
    const unsigned short* __restrict__ actin,
    const unsigned short* __restrict__ wpk,
    const float* __restrict__ bias,
    unsigned short* __restrict__ actout,
    float* __restrict__ partial)
{
  constexpr int LINP  = LIN + 32;
  constexpr int LOUTP = LOUT + 32;
  constexpr int SPANB = 8*LT + 64;
  constexpr int SC    = SPANB/16;
  constexpr int CA    = 2*NBT*SC;
  static_assert(CA <= 256, "CA");
  constexpr int ASZ   = CA*16;
  constexpr int BSZ   = 16384;
  constexpr int MT    = 128*LOUT;
  constexpr int MTILES= MT/128;
  constexpr int NT    = COUT/128;
  constexpr int NSTEP = CIN/2/KSPLIT;
  constexpr int GRID  = MTILES*NT*KSPLIT;
  static_assert(GRID % 8 == 0, "grid%8");
  __shared__ __align__(16) char smem[2*(BSZ+ASZ)];
  char* Bb = smem;
  char* Ab = smem + 2*BSZ;

  // XCD-aware swizzle
  int bid = (blockIdx.x & 7)*(GRID/8) + (blockIdx.x >> 3);
  int mt = bid % MTILES; bid /= MTILES;
  int nt = bid % NT;     int z = bid / NT;
  int b0 = (mt*128)/LOUT;
  int l0 = (mt*128)%LOUT;
  int cobase = nt*128;
  int s0 = z*NSTEP, s1 = s0 + NSTEP;

  int tid = threadIdx.x; int lane = tid&63; int wid = tid>>6;
  int wm = wid>>1, wn = wid&1;
  int l15 = lane&15, kg = lane>>4;

  int aq_c=0, aq_b=0, aq_j=0; bool a_act = tid < CA;
  { int q = tid; aq_c = q/(NBT*SC); int r = q%(NBT*SC); aq_b = r/SC; aq_j = r%SC; }

  auto STAGE = [&](int st){
    int buf = st&1;
    #pragma unroll
    for(int i=0;i<4;i++){
      int qb = tid + i*256;
      int col = qb>>3; int j = qb&7;
      const char* src = (const char*)wpk + (size_t)(cobase+col)*(CIN*64) + (size_t)st*128
                        + ((j*16) ^ ((col&7)<<4));
      gld_lds16(src, Bb + buf*BSZ + qb*16);
    }
    if(a_act){
      int ci = 2*st + aq_c;
      const char* src = (const char*)actin
          + 2*((size_t)((b0+aq_b)*CIN + ci)*LINP + 4*l0) + aq_j*16;
      gld_lds16(src, Ab + buf*ASZ + tid*16);
    }
  };

  int abyte[2][4], bbyte[2][4];
  #pragma unroll
  for(int c=0;c<2;c++){
    #pragma unroll
    for(int mf=0;mf<4;mf++){
      int r = wm*64 + mf*16 + l15;
      int bp = (NBT>1) ? (r/LT) : 0;
      int ll = (NBT>1) ? (r%LT) : r;
      abyte[c][mf] = (c*NBT + bp)*SPANB + 8*ll + 16*kg;
    }
    #pragma unroll
    for(int nf=0;nf<4;nf++){
      int col = wn*64 + nf*16 + l15;
      bbyte[c][nf] = col*128 + ((c*64 + 16*kg) ^ ((col&7)<<4));
    }
  }

  const f32x4 vz = {0.f,0.f,0.f,0.f};
  f32x4 acc[4][4];
  #pragma unroll
  for(int i=0;i<4;i++)
    #pragma unroll
    for(int j=0;j<4;j++) acc[i][j] = vz;

  STAGE(s0);
  __syncthreads();
  for(int s=s0;s<s1;s++){
    if(s+1<s1) STAGE(s+1);
    const char* Ac = Ab + (s&1)*ASZ;
    const char* Bc = Bb + (s&1)*BSZ;
    #pragma unroll
    for(int c=0;c<2;c++){
      bf16x8 af[4], bfv[4];
      #pragma unroll
      for(int mf=0;mf<4;mf++){
        const char* ap = Ac + abyte[c][mf];
        union { unsigned long long u[2]; bf16x8 v; } t;
        t.u[0] = *(const unsigned long long*)ap;
        t.u[1] = *(const unsigned long long*)(ap+8);
        af[mf] = t.v;
      }
      #pragma unroll
      for(int nf=0;nf<4;nf++) bfv[nf] = *(const bf16x8*)(Bc + bbyte[c][nf]);
      #pragma unroll
      for(int mf=0;mf<4;mf++)
        #pragma unroll
        for(int nf=0;nf<4;nf++)
          acc[mf][nf] = __builtin_amdgcn_mfma_f32_16x16x32_bf16(af[mf], bfv[nf], acc[mf][nf], 0,0,0);
    }
    __syncthreads();
  }

  if constexpr (KSPLIT == 1){
    #pragma unroll
    for(int nf=0;nf<4;nf++){
      int co = cobase + wn*64 + nf*16 + l15;
      float bv = bias[co];
      #pragma unroll
      for(int mf=0;mf<4;mf++){
        int m = wm*64 + mf*16 + 4*kg;
        int bp = (NBT>1) ? (m/LT) : 0;
        int ll = (NBT>1) ? (m%LT) : m;
        f32x4 a = acc[mf][nf];
        ushort4 o;
        o.x = f2bf(fmaxf(a[0]+bv,0.f));
        o.y = f2bf(fmaxf(a[1]+bv,0.f));
        o.z = f2bf(fmaxf(a[2]+bv,0.f));
        o.w = f2bf(fmaxf(a[3]+bv,0.f));
        size_t off = ((size_t)((b0+bp)*COUT + co))*LOUTP + 16 + l0 + ll;
        *(ushort4*)&actout[off] = o;
      }
    }
  } else {
    #pragma unroll
    for(int nf=0;nf<4;nf++){
      int co = cobase + wn*64 + nf*16 + l15;
      #pragma unroll
      for(int mf=0;mf<4;mf++){
        int mloc = wm*64 + mf*16 + 4*kg;
        int mglob = mt*128 + mloc;
        *(f32x4*)&partial[((size_t)(z*COUT + co))*MT + mglob] = acc[mf][nf];
      }
    }
  }
}

// ---------------- reduce K-split partials -> bf16 padded act ----------------
template<int COUT, int MT, int LOUT, int KS>
__global__ __launch_bounds__(256) void reduce_k(const float* __restrict__ partial,
    const float* __restrict__ bias, unsigned short* __restrict__ actout){
  int idx = blockIdx.x*256 + threadIdx.x;
  if(idx >= COUT*(MT/4)) return;
  int m4 = idx % (MT/4); int co = idx / (MT/4);
  int m = m4*4;
  float4 a = *(const float4*)&partial[(size_t)co*MT + m];
  #pragma unroll
  for(int zz=1; zz<KS; zz++){
    float4 b = *(const float4*)&partial[((size_t)(zz*COUT + co))*MT + m];
    a.x += b.x; a.y += b.y; a.z += b.z; a.w += b.w;
  }
  float bv = bias[co];
  int b_ = m / LOUT, l = m % LOUT;
  ushort4 o;
  o.x = f2bf(fmaxf(a.x+bv,0.f));
  o.y = f2bf(fmaxf(a.y+bv,0.f));
  o.z = f2bf(fmaxf(a.z+bv,0.f));
  o.w = f2bf(fmaxf(a.w+bv,0.f));
  *(ushort4*)&actout[((size_t)(b_*COUT + co))*(LOUT+32) + 16 + l] = o;
}

// ---------------- gather act4 -> hflatb bf16 [B][8192], pre-swizzled by batch ----------------
__global__ __launch_bounds__(256) void gather_k(const unsigned short* __restrict__ act4,
    unsigned short* __restrict__ hflatb){
  __shared__ unsigned short trans[8][260];
  int b = blockIdx.x >> 2, ct = blockIdx.x & 3;
  int c0 = ct*256;
  int tid = threadIdx.x;
  uint4 v = *(const uint4*)&act4[((size_t)(b*1024 + c0 + tid))*40 + 16];
  unsigned short* pv = (unsigned short*)&v;
  #pragma unroll
  for(int l=0;l<8;l++) trans[l][tid] = pv[l];
  __syncthreads();
  int l = tid>>5, cg_ = tid&31;
  uint4 o;
  unsigned short* po = (unsigned short*)&o;
  #pragma unroll
  for(int e=0;e<8;e++) po[e] = trans[l][cg_*8+e];
  int G = l*128 + ct*32 + cg_;
  *(uint4*)&hflatb[(size_t)b*8192 + (size_t)((G ^ (b&7))*8)] = o;
}

// ---------------- pack proj weights v2 (8-wide): [1024 n][8192 d] bf16 ----------------
__global__ __launch_bounds__(256) void packwproj2_k(const float* __restrict__ phw,
    const float* __restrict__ pcw, unsigned short* __restrict__ wproj){
  int idx = blockIdx.x*256 + threadIdx.x;     // 1048576 = 1024 n x 1024 d-octets
  if(idx >= 1048576) return;
  int n = idx >> 10; int d = (idx & 1023)*8;
  const float* src = ((n < 512) ? (phw + (size_t)n*8192) : (pcw + (size_t)(n-512)*8192)) + d;
  float4 a = *(const float4*)src;
  float4 b = *(const float4*)(src+4);
  ushort4 o0, o1;
  o0.x=f2bf(a.x); o0.y=f2bf(a.y); o0.z=f2bf(a.z); o0.w=f2bf(a.w);
  o1.x=f2bf(b.x); o1.y=f2bf(b.y); o1.z=f2bf(b.z); o1.w=f2bf(b.w);
  *(ushort4*)&wproj[(size_t)idx*8]     = o0;
  *(ushort4*)&wproj[(size_t)idx*8 + 4] = o1;
}

// ---------------- pack E vectors (wave-parallel) ----------------
__global__ __launch_bounds__(256) void pack_e2_k(const float* __restrict__ wih,
    const float* __restrict__ bih, const float* __restrict__ bhh,
    const float* __restrict__ embw, const float* __restrict__ embb,
    float* __restrict__ E0, float* __restrict__ E1, float* __restrict__ BX, float* __restrict__ B0){
  int row = blockIdx.x*4 + (threadIdx.x>>6);
  int lane = threadIdx.x & 63;
  const float* wr = wih + (size_t)row*512;
  float e0=0.f, e1=0.f, bx=0.f;
  #pragma unroll
  for(int e=0;e<8;e++){
    int j = lane + 64*e;
    float wv = wr[j];
    e0 = fmaf(wv, embw[j*2+0], e0);
    e1 = fmaf(wv, embw[j*2+1], e1);
    bx = fmaf(wv, embb[j], bx);
  }
  #pragma unroll
  for(int off=32; off; off>>=1){
    e0 += __shfl_down(e0, off, 64);
    e1 += __shfl_down(e1, off, 64);
    bx += __shfl_down(bx, off, 64);
  }
  if(lane==0){
    int u = row & 511, g = row >> 9;
    float b0v = bih[row] + bhh[row];
    E0[u*4+g] = e0; E1[u*4+g] = e1; BX[u*4+g] = bx + b0v; B0[u*4+g] = b0v;
  }
}

// ---------------- projection via MFMA, K-split: grid 128 = 8 nt x 16 zk ----------------
__global__ __launch_bounds__(256,2) void projm2_k(
    const unsigned short* __restrict__ hflatb,
    const unsigned short* __restrict__ wproj,
    float* __restrict__ partial)      // [16 zk][1024 n][128 b]
{
  __shared__ __align__(16) char smem[2*(16384+16384)];
  char* Bb = smem;
  char* Ab = smem + 32768;
  int bid = blockIdx.x;
  int zk = bid & 15, nt = bid >> 4;
  int n0 = nt*128;
  int tid = threadIdx.x, lane = tid&63, wid = tid>>6;
  int wm = wid>>1, wn = wid&1;
  int l15 = lane&15, kg = lane>>4;

  auto STAGE = [&](int kc){
    int buf = kc&1;
    #pragma unroll
    for(int i=0;i<4;i++){
      int q = tid + i*256;
      int col = q>>3, j = q&7;
      const char* src = (const char*)wproj + (size_t)(n0+col)*16384
                        + (size_t)zk*1024 + kc*128 + ((j*16) ^ ((col&7)<<4));
      gld_lds16(src, Bb + buf*16384 + q*16);
    }
    #pragma unroll
    for(int i=0;i<4;i++){
      int q = tid + i*256;
      int row = q>>3, j = q&7;
      // hflatb is ALREADY pre-swizzled in global -> stage LINEARLY.
      const char* src = (const char*)hflatb + (size_t)row*16384
                        + (size_t)zk*1024 + kc*128 + j*16;
      gld_lds16(src, Ab + buf*16384 + q*16);
    }
  };

  const f32x4 vz = {0.f,0.f,0.f,0.f};
  f32x4 acc[4][4];
  #pragma unroll
  for(int i=0;i<4;i++)
    #pragma unroll
    for(int j=0;j<4;j++) acc[i][j] = vz;

  STAGE(0);
  __syncthreads();
  for(int kc=0;kc<8;kc++){
    if(kc<7) STAGE(kc+1);
    const char* Ac = Ab + (kc&1)*16384;
    const char* Bc = Bb + (kc&1)*16384;
    #pragma unroll
    for(int c=0;c<2;c++){
      bf16x8 af[4], bfv[4];
      #pragma unroll
      for(int mf=0;mf<4;mf++){
        int row = wm*64 + mf*16 + l15;
        af[mf] = *(const bf16x8*)(Ac + row*128 + ((c*64 + kg*16) ^ ((row&7)<<4)));
      }
      #pragma unroll
      for(int nf=0;nf<4;nf++){
        int col = wn*64 + nf*16 + l15;
        bfv[nf] = *(const bf16x8*)(Bc + col*128 + ((c*64 + kg*16) ^ ((col&7)<<4)));
      }
      #pragma unroll
      for(int mf=0;mf<4;mf++)
        #pragma unroll
        for(int nf=0;nf<4;nf++)
          acc[mf][nf] = __builtin_amdgcn_mfma_f32_16x16x32_bf16(af[mf], bfv[nf], acc[mf][nf], 0,0,0);
    }
    __syncthreads();
  }
  #pragma unroll
  for(int nf=0;nf<4;nf++){
    int n = n0 + wn*64 + nf*16 + l15;
    #pragma unroll
    for(int mf=0;mf<4;mf++){
      int m = wm*64 + mf*16 + kg*4;
      *(f32x4*)&partial[((size_t)zk*1024 + n)*128 + m] = acc[mf][nf];
    }
  }
}

// ---------------- reduce proj partials -> hbf0 (swizzled bf16) + cbuf ----------------
__global__ __launch_bounds__(256) void reduceproj_k(const float* __restrict__ partial,
    const float* __restrict__ phb, const float* __restrict__ pcb,
    unsigned short* __restrict__ hbf0, float* __restrict__ cbuf){
  int idx = blockIdx.x*256 + threadIdx.x;    // 32768 = 1024 n x 32 b-quads
  int n = idx >> 5; int b4 = (idx & 31)*4;
  const float* p = partial + (size_t)n*128 + b4;
  float4 a = *(const float4*)p;
  #pragma unroll
  for(int z=1; z<16; z++){
    float4 v = *(const float4*)(p + (size_t)z*131072);
    a.x+=v.x; a.y+=v.y; a.z+=v.z; a.w+=v.w;
  }
  float av[4] = {a.x, a.y, a.z, a.w};
  if(n < 512){
    float bv = phb[n];
    #pragma unroll
    for(int j=0;j<4;j++){
      int b = b4 + j;
      hbf0[(size_t)b*512 + (n ^ ((b&7)<<3))] = f2bf(av[j] + bv);
    }
  } else {
    float bv = pcb[n-512];
    #pragma unroll
    for(int j=0;j<4;j++){
      int b = b4 + j;
      cbuf[(size_t)b*512 + (n-512)] = av[j] + bv;
    }
  }
}

// ---------------- LSTM step v6: W in regs, dual MFMA accumulator chains ----------------
__global__ __launch_bounds__(256) void lstm6_k(
    const unsigned short* __restrict__ hbfprev,
    unsigned short* __restrict__ hbfnext,
    float* __restrict__ cbuf,
    const uint4* __restrict__ wq,
    const float4* __restrict__ E0v, const float4* __restrict__ E1v,
    const float4* __restrict__ BXv, const float4* __restrict__ B0v,
    const float* __restrict__ lf0w, const float* __restrict__ lf0b,
    const float* __restrict__ uvw, const float* __restrict__ uvb,
    float* __restrict__ dout, int t)
{
  __shared__ __align__(16) char A[16384];        // 16 rows x 1024 B (XOR-swizzled)
  __shared__ __align__(16) float gates[16][68];
  __shared__ float red0[16][17], red1[16][17];
  __shared__ float lf_s[16], uv_s[16];

  int bid = blockIdx.x;
  int ut = bid & 31, bt = bid >> 5;
  int b0 = bt*16;
  int tid = threadIdx.x, lane = tid&63, wn = tid>>6;
  int l15 = lane&15, kg = lane>>4;

  // stage h (16 KB) into LDS; W frags direct to registers
  #pragma unroll
  for(int i=0;i<4;i++){
    int q = i*256 + tid;
    gld_lds16((const char*)hbfprev + (size_t)b0*1024 + q*16, A + q*16);
  }
  const uint4* wbase = wq + ((size_t)(ut*4+wn)*16)*64 + lane;
  bf16x8 w[16];
  #pragma unroll
  for(int ks=0;ks<16;ks++){
    uint4 v = wbase[(size_t)ks*64];
    w[ks] = *(bf16x8*)&v;
  }
  asm volatile("s_waitcnt vmcnt(0)");
  __syncthreads();

  // gates GEMM: dual independent accumulator chains (8+8) to halve dep latency
  const f32x4 vz = {0.f,0.f,0.f,0.f};
  f32x4 acc0 = vz, acc1 = vz;
  int c = wn*16 + l15;
  int aswz = (l15&7)<<4;
  #pragma unroll
  for(int ks=0; ks<8; ks++){
    bf16x8 af0 = *(const bf16x8*)(A + l15*1024 + (((2*ks)*64 + kg*16) ^ aswz));
    acc0 = __builtin_amdgcn_mfma_f32_16x16x32_bf16(af0, w[2*ks], acc0, 0,0,0);
    bf16x8 af1 = *(const bf16x8*)(A + l15*1024 + (((2*ks+1)*64 + kg*16) ^ aswz));
    acc1 = __builtin_amdgcn_mfma_f32_16x16x32_bf16(af1, w[2*ks+1], acc1, 0,0,0);
  }
  f32x4 acc = acc0 + acc1;
  #pragma unroll
  for(int j=0;j<4;j++) gates[kg*4+j][c] = acc[j];

  // heads for output t-1 (from staged h_prev)
  int hb = tid & 15, hs = tid >> 4;
  if(t > 0){
    float p0 = 0.f, p1 = 0.f;
    #pragma unroll
    for(int j=0;j<4;j++){
      bf16x8 hv = *(const bf16x8*)(A + hb*1024 + ((hs*64 + j*16) ^ ((hb&7)<<4)));
      #pragma unroll
      for(int e=0;e<8;e++){
        float h = bf2f((unsigned short)hv[e]);
        int k = hs*32 + j*8 + e;
        p0 = fmaf(h, lf0w[k], p0);
        p1 = fmaf(h, uvw[k], p1);
      }
    }
    red0[hs][hb] = p0; red1[hs][hb] = p1;
  }
  __syncthreads();
  if(t > 0 && tid < 16){
    float a0=0.f, a1=0.f;
    #pragma unroll
    for(int s2=0;s2<16;s2++){ a0 += red0[s2][tid]; a1 += red1[s2][tid]; }
    a0 += lf0b[0];
    a1 = sigm(a1 + uvb[0]);
    lf_s[tid] = a0; uv_s[tid] = a1;
    if(ut == 0){
      dout[(size_t)(b0+tid)*(2*NSTEPS) + (t-1)*2 + 0] = a0;
      dout[(size_t)(b0+tid)*(2*NSTEPS) + (t-1)*2 + 1] = a1;
    }
  }
  __syncthreads();

  // epilogue: one (b, u) per thread: 16 b x 16 u
  {
    int b = tid & 15, ul = tid >> 4;
    int u = ut*16 + ul;
    float4 g4 = *(const float4*)&gates[b][ul*4];
    float4 xp;
    if(t == 0){
      xp = B0v[u];
    } else {
      float lf = lf_s[b], uvv = uv_s[b];
      float4 e0 = E0v[u], e1 = E1v[u], bx = BXv[u];
      xp.x = fmaf(lf, e0.x, fmaf(uvv, e1.x, bx.x));
      xp.y = fmaf(lf, e0.y, fmaf(uvv, e1.y, bx.y));
      xp.z = fmaf(lf, e0.z, fmaf(uvv, e1.z, bx.z));
      xp.w = fmaf(lf, e0.w, fmaf(uvv, e1.w, bx.w));
    }
    float gi = sigm(g4.x + xp.x);
    float gf = sigm(g4.y + xp.y);
    float gg = tanhf(g4.z + xp.z);
    float go = sigm(g4.w + xp.w);
    size_t off = (size_t)(b0+b)*512 + u;
    float cn = fmaf(gf, cbuf[off], gi*gg);
    cbuf[off] = cn;
    float hn = go * tanhf(cn);
    hbfnext[(size_t)(b0+b)*512 + (u ^ ((b&7)<<3))] = f2bf(hn);
  }
}

// ---------------- final output (t = 199) from bf16 h ----------------
__global__ __launch_bounds__(64) void final_k(const unsigned short* __restrict__ hbf,
    const float* __restrict__ lf0w, const float* __restrict__ lf0b,
    const float* __restrict__ uvw, const float* __restrict__ uvb,
    float* __restrict__ dout){
  int b = blockIdx.x; int lane = threadIdx.x;
  float p0=0.f, p1=0.f;
  for(int k=lane;k<512;k+=64){
    float hv = bf2f(hbf[(size_t)b*512 + (k ^ ((b&7)<<3))]);
    p0 = fmaf(hv, lf0w[k], p0);
    p1 = fmaf(hv, uvw[k], p1);
  }
  for(int off=32; off; off>>=1){
    p0 += __shfl_down(p0, off, 64);
    p1 += __shfl_down(p1, off, 64);
  }
  if(lane==0){
    dout[(size_t)b*(2*NSTEPS) + 199*2 + 0] = p0 + lf0b[0];
    dout[(size_t)b*(2*NSTEPS) + 199*2 + 1] = sigm(p1 + uvb[0]);
  }
}

extern "C" void kernel_launch(void* const* d_in, const int* in_sizes, int n_in,
                              void* d_out, int out_size, void* d_ws, size_t ws_size,
                              hipStream_t stream) {
  const float* x    = (const float*)d_in[0];
  const float* cw0  = (const float*)d_in[2];  const float* cb0 = (const float*)d_in[3];
  const float* cw1  = (const float*)d_in[4];  const float* cb1 = (const float*)d_in[5];
  const float* cw2  = (const float*)d_in[6];  const float* cb2 = (const float*)d_in[7];
  const float* cw3  = (const float*)d_in[8];  const float* cb3 = (const float*)d_in[9];
  const float* cw4  = (const float*)d_in[10]; const float* cb4 = (const float*)d_in[11];
  const float* phw  = (const float*)d_in[12]; const float* phb = (const float*)d_in[13];
  const float* pcw  = (const float*)d_in[14]; const float* pcb = (const float*)d_in[15];
  const float* wih  = (const float*)d_in[16]; const float* whh = (const float*)d_in[17];
  const float* bih  = (const float*)d_in[18]; const float* bhh = (const float*)d_in[19];
  const float* lf0w = (const float*)d_in[20]; const float* lf0b = (const float*)d_in[21];
  const float* uvw  = (const float*)d_in[22]; const float* uvb  = (const float*)d_in[23];
  const float* embw = (const float*)d_in[24]; const float* embb = (const float*)d_in[25];
  float* dout = (float*)d_out;

  float* ws = (float*)d_ws;
  unsigned short* act0 = (unsigned short*)ws;
  unsigned short* act2 = (unsigned short*)ws;
  unsigned short* act4 = (unsigned short*)ws;
  float*          part = ws + 2883584;                      // conv partials
  unsigned short* wproj= (unsigned short*)(ws + 2883584);   // proj weights (after convs)
  unsigned short* hflatb=(unsigned short*)(ws + 7077888);   // 2 MB
  unsigned short* act1 = (unsigned short*)(ws + 8519680);
  unsigned short* act3 = (unsigned short*)(ws + 8519680);
  float*          ppart= ws + 8519680;                      // proj partials (8 MB, region B)
  unsigned short* wpk1 = (unsigned short*)(ws + 12976128);
  unsigned short* wpk2 = wpk1 + 262144;
  unsigned short* wpk3 = wpk2 + 1048576;
  unsigned short* wpk4 = wpk3 + 4194304;
  uint4*          wq   = (uint4*)(ws + 24117248);           // 2 MB
  float*  E0  = ws + 24641536;
  float*  E1  = E0 + 2048;
  float*  BX  = E1 + 2048;
  float*  B0  = BX + 2048;
  float*  cb  = ws + 24649728;
  unsigned short* hbf0 = (unsigned short*)(ws + 24715264);
  unsigned short* hbf1 = (unsigned short*)(ws + 24748032);

  // ---- fused prep (vectorized packs + pads) ----
  prep2_k<<<23040, 256, 0, stream>>>(cw1, cw2, cw3, cw4,
      wpk1, wpk2, wpk3, wpk4, whh, wq, act0, act1);
  pack_e2_k<<<512, 256, 0, stream>>>(wih, bih, bhh, embw, embb, E0, E1, BX, B0);

  // ---- conv stack ----
  conv0_k<<<1024, 256, 0, stream>>>(x, cw0, cb0, act0);
  conv_mfma_k<64,2048,512,128,1,128,1><<<512, 256, 0, stream>>>(act0, wpk1, cb1, act1, nullptr);
  zpad_k<<<(128*256*8+255)/256, 256, 0, stream>>>(act2, 128*256, 128);
  conv_mfma_k<128,512,128,128,1,256,1><<<256, 256, 0, stream>>>(act1, wpk2, cb2, act2, nullptr);
  zpad_k<<<(128*512*8+255)/256, 256, 0, stream>>>(act3, 128*512, 32);
  conv_mfma_k<256,128,32,32,4,512,2><<<256, 256, 0, stream>>>(act2, wpk3, cb3, nullptr, part);
  reduce_k<512,4096,32,2><<<2048, 256, 0, stream>>>(part, cb3, act3);
  conv_mfma_k<512,32,8,8,16,1024,4><<<256, 256, 0, stream>>>(act3, wpk4, cb4, nullptr, part);
  reduce_k<1024,1024,8,4><<<1024, 256, 0, stream>>>(part, cb4, act4);

  // ---- proj (MFMA, K-split) ----
  packwproj2_k<<<4096, 256, 0, stream>>>(phw, pcw, wproj);
  gather_k<<<512, 256, 0, stream>>>(act4, hflatb);
  projm2_k<<<128, 256, 0, stream>>>(hflatb, wproj, ppart);
  reduceproj_k<<<128, 256, 0, stream>>>(ppart, phb, pcb, hbf0, cb);

  // ---- LSTM (per-step launches; kernel-launch boundary is the cheap sync) ----
  for(int t=0; t<NSTEPS; t++){
    unsigned short* hp = (t & 1) ? hbf1 : hbf0;
    unsigned short* hn = (t & 1) ? hbf0 : hbf1;
    lstm6_k<<<256, 256, 0, stream>>>(hp, hn, cb, wq,
        (const float4*)E0, (const float4*)E1, (const float4*)BX, (const float4*)B0,
        lf0w, lf0b, uvw, uvb, dout, t);
  }
  final_k<<<128, 64, 0, stream>>>(hbf0, lf0w, lf0b, uvw, uvb, dout);
}